// Round 1
// baseline (14375.710 us; speedup 1.0000x reference)
//
#include <hip/hip_runtime.h>
#include <math.h>

#define T_LEN   4096
#define CCH     256
#define TILE    16
#define NLAYERS 40

// ---------------------------------------------------------------------------
// h[c][t] = tanh(emb_w[x[t]][c]); also zero skip_sum
// ---------------------------------------------------------------------------
__global__ __launch_bounds__(256) void embed_kernel(
    const int* __restrict__ x, const float* __restrict__ emb_w,
    float* __restrict__ h, float* __restrict__ skip)
{
    int idx = blockIdx.x * 256 + threadIdx.x;
    if (idx < CCH * T_LEN) {
        int c = idx / T_LEN, t = idx % T_LEN;
        h[idx]    = tanhf(emb_w[x[t] * CCH + c]);
        skip[idx] = 0.0f;
    }
}

// ---------------------------------------------------------------------------
// condf[o][f] = sum_a cond_w[o][a] * y[a][f]   (o<20480, f<16, a<80)
// ---------------------------------------------------------------------------
__global__ __launch_bounds__(256) void cond_kernel(
    const float* __restrict__ cond_w, const float* __restrict__ y,
    float* __restrict__ condf)
{
    int idx = blockIdx.x * 256 + threadIdx.x;
    if (idx < 20480 * 16) {
        int o = idx >> 4, f = idx & 15;
        float acc = 0.0f;
        for (int a = 0; a < 80; ++a)
            acc += cond_w[o * 80 + a] * y[a * 16 + f];
        condf[idx] = acc;
    }
}

// ---------------------------------------------------------------------------
// One WaveNet layer. Grid: T_LEN/TILE workgroups of 512 threads.
// Each WG owns columns [t0, t0+TILE).
//   z = W0 @ h[t-d] + W1 @ h[t] + b + cond(t)          (512 rows)
//   u = tanh(z[:256]) * sigmoid(z[256:])               (256 rows)
//   o = Wo @ u (+ bo)                                  (512 rows, 256 if last)
//   h_out = h_in + o[:256] ; skip += o[256:]  (last: skip += o)
// ---------------------------------------------------------------------------
__global__ __launch_bounds__(512) void layer_kernel(
    const float* __restrict__ h_in,
    float* __restrict__ h_out,
    float* __restrict__ skip,
    const float* __restrict__ condf,   // [20480][16]
    const float* __restrict__ lw,      // [512][256][2]
    const float* __restrict__ lb,      // [512]
    const float* __restrict__ wow,     // [512][256] (last: [256][256])
    const float* __restrict__ wob,     // [512] (last: [256])
    int d, int layer, int is_last)
{
    __shared__ float h0[CCH][TILE];   // h[t-d]
    __shared__ float h1[CCH][TILE];   // h[t]
    __shared__ float zl[2 * CCH][TILE];
    __shared__ float ul[CCH][TILE];

    const int tid = threadIdx.x;
    const int t0  = blockIdx.x * TILE;

    // load h tiles (zero-pad t-d < 0)
    for (int k = tid; k < CCH * TILE; k += 512) {
        int r = k / TILE, ci = k % TILE;
        int t  = t0 + ci;
        int tm = t - d;
        h1[r][ci] = h_in[r * T_LEN + t];
        h0[r][ci] = (tm >= 0) ? h_in[r * T_LEN + tm] : 0.0f;
    }
    __syncthreads();

    const int col = tid & 15;
    const int rg  = tid >> 4;     // 0..31
    const int r0  = rg * 16;
    const int t   = t0 + col;

    // conditioning interpolation factors (match jnp exactly: /256 is exact pow2)
    float pos = fmaxf((t + 0.5f) * (1.0f / 256.0f) - 0.5f, 0.0f);
    int   i0  = (int)pos;
    int   i1  = min(i0 + 1, 15);
    float fw  = pos - (float)i0;

    // ---- phase 1: conv matmul, rows r0..r0+15 ----
    float acc[16];
    #pragma unroll
    for (int j = 0; j < 16; ++j) acc[j] = 0.0f;

    const float2* lw2 = (const float2*)lw;   // [512][256] of (tap0, tap1)
    for (int c = 0; c < CCH; ++c) {
        float x0 = h0[c][col];
        float x1 = h1[c][col];
        #pragma unroll
        for (int j = 0; j < 16; ++j) {
            float2 w = lw2[(r0 + j) * 256 + c];
            acc[j] += w.x * x0 + w.y * x1;
        }
    }
    #pragma unroll
    for (int j = 0; j < 16; ++j) {
        int r = r0 + j;
        const float* cf = condf + ((size_t)(layer * 512 + r)) * 16;
        float cv = cf[i0] * (1.0f - fw) + cf[i1] * fw;
        zl[r][col] = acc[j] + lb[r] + cv;
    }
    __syncthreads();

    // ---- gating ----
    if (rg < 16) {
        #pragma unroll
        for (int j = 0; j < 16; ++j) {
            int r = r0 + j;
            float a = zl[r][col];
            float g = zl[r + CCH][col];
            ul[r][col] = tanhf(a) * (1.0f / (1.0f + expf(-g)));
        }
    }
    __syncthreads();

    // ---- phase 2: output matmul ----
    const int nrows = is_last ? 256 : 512;
    if (r0 < nrows) {
        float acc2[16];
        #pragma unroll
        for (int j = 0; j < 16; ++j) acc2[j] = 0.0f;
        for (int c = 0; c < CCH; ++c) {
            float uv = ul[c][col];
            #pragma unroll
            for (int j = 0; j < 16; ++j)
                acc2[j] += wow[(r0 + j) * 256 + c] * uv;
        }
        #pragma unroll
        for (int j = 0; j < 16; ++j) {
            int r = r0 + j;
            float o = acc2[j] + wob[r];
            if (is_last) {
                skip[r * T_LEN + t] += o;
            } else if (r < CCH) {
                h_out[r * T_LEN + t] = h1[r][col] + o;
            } else {
                skip[(r - CCH) * T_LEN + t] += o;
            }
        }
    }
}

// ---------------------------------------------------------------------------
// out = end2 @ relu(end1 @ relu(skip) + b1) + b2
// ---------------------------------------------------------------------------
__global__ __launch_bounds__(256) void head_kernel(
    const float* __restrict__ skip,
    const float* __restrict__ e1w, const float* __restrict__ e1b,
    const float* __restrict__ e2w, const float* __restrict__ e2b,
    float* __restrict__ out)
{
    __shared__ float s[CCH][TILE];
    __shared__ float m[CCH][TILE];
    const int tid = threadIdx.x;
    const int t0  = blockIdx.x * TILE;

    for (int k = tid; k < CCH * TILE; k += 256) {
        int r = k / TILE, ci = k % TILE;
        s[r][ci] = fmaxf(skip[r * T_LEN + t0 + ci], 0.0f);
    }
    __syncthreads();

    const int col = tid & 15;
    const int rg  = tid >> 4;    // 0..15
    const int r0  = rg * 16;

    float acc[16];
    #pragma unroll
    for (int j = 0; j < 16; ++j) acc[j] = 0.0f;
    for (int c = 0; c < CCH; ++c) {
        float sv = s[c][col];
        #pragma unroll
        for (int j = 0; j < 16; ++j)
            acc[j] += e1w[(r0 + j) * 256 + c] * sv;
    }
    #pragma unroll
    for (int j = 0; j < 16; ++j)
        m[r0 + j][col] = fmaxf(acc[j] + e1b[r0 + j], 0.0f);
    __syncthreads();

    #pragma unroll
    for (int j = 0; j < 16; ++j) acc[j] = 0.0f;
    for (int c = 0; c < CCH; ++c) {
        float mv = m[c][col];
        #pragma unroll
        for (int j = 0; j < 16; ++j)
            acc[j] += e2w[(r0 + j) * 256 + c] * mv;
    }
    const int t = t0 + col;
    #pragma unroll
    for (int j = 0; j < 16; ++j)
        out[(r0 + j) * T_LEN + t] = acc[j] + e2b[r0 + j];
}

// ---------------------------------------------------------------------------
extern "C" void kernel_launch(void* const* d_in, const int* in_sizes, int n_in,
                              void* d_out, int out_size, void* d_ws, size_t ws_size,
                              hipStream_t stream)
{
    const int*   x       = (const int*)  d_in[0];
    const float* y       = (const float*)d_in[1];
    // d_in[2] = zeropad (unused by reference body)
    const float* emb_w   = (const float*)d_in[3];
    const float* cond_w  = (const float*)d_in[4];
    const float* layer_w = (const float*)d_in[5];
    const float* layer_b = (const float*)d_in[6];
    const float* wo_w    = (const float*)d_in[7];
    const float* wo_b    = (const float*)d_in[8];
    const float* lwo_w   = (const float*)d_in[9];
    const float* lwo_b   = (const float*)d_in[10];
    const float* e1w     = (const float*)d_in[11];
    const float* e1b     = (const float*)d_in[12];
    const float* e2w     = (const float*)d_in[13];
    const float* e2b     = (const float*)d_in[14];
    float* out = (float*)d_out;

    char* ws = (char*)d_ws;
    float* hA    = (float*)(ws);
    float* hB    = (float*)(ws + 4u * 1024u * 1024u);
    float* skip  = (float*)(ws + 8u * 1024u * 1024u);
    float* condf = (float*)(ws + 12u * 1024u * 1024u);

    embed_kernel<<<(CCH * T_LEN + 255) / 256, 256, 0, stream>>>(x, emb_w, hA, skip);
    cond_kernel<<<(20480 * 16 + 255) / 256, 256, 0, stream>>>(cond_w, y, condf);

    static const int dil[10] = {1, 2, 4, 8, 16, 32, 64, 128, 256, 512};
    float* hin = hA;
    float* hout = hB;
    for (int i = 0; i < NLAYERS; ++i) {
        int d = dil[i % 10];
        int is_last = (i == NLAYERS - 1) ? 1 : 0;
        const float* wow = is_last ? lwo_w : (wo_w + (size_t)i * 512 * 256);
        const float* wob = is_last ? lwo_b : (wo_b + (size_t)i * 512);
        layer_kernel<<<T_LEN / TILE, 512, 0, stream>>>(
            hin, hout, skip, condf,
            layer_w + (size_t)i * 512 * 256 * 2,
            layer_b + (size_t)i * 512,
            wow, wob, d, i, is_last);
        float* tmp = hin; hin = hout; hout = tmp;
    }

    head_kernel<<<T_LEN / TILE, 256, 0, stream>>>(skip, e1w, e1b, e2w, e2b, out);
}

// Round 2
// 2796.125 us; speedup vs baseline: 5.1413x; 5.1413x over previous
//
#include <hip/hip_runtime.h>
#include <math.h>

#define T_LEN   4096
#define NLAYERS 40

// ---------------------------------------------------------------------------
// h[c][t] = tanh(emb_w[x[t]][c]); also zero skip_sum
// ---------------------------------------------------------------------------
__global__ __launch_bounds__(256) void embed_kernel(
    const int* __restrict__ x, const float* __restrict__ emb_w,
    float* __restrict__ h, float* __restrict__ skip)
{
    int idx = blockIdx.x * 256 + threadIdx.x;
    if (idx < 256 * T_LEN) {
        int c = idx / T_LEN, t = idx % T_LEN;
        h[idx]    = tanhf(emb_w[x[t] * 256 + c]);
        skip[idx] = 0.0f;
    }
}

// ---------------------------------------------------------------------------
// condf[o][f] = sum_a cond_w[o][a] * y[a][f]   (o<20480, f<16, a<80)
// ---------------------------------------------------------------------------
__global__ __launch_bounds__(256) void cond_kernel(
    const float* __restrict__ cond_w, const float* __restrict__ y,
    float* __restrict__ condf)
{
    int idx = blockIdx.x * 256 + threadIdx.x;
    if (idx < 20480 * 16) {
        int o = idx >> 4, f = idx & 15;
        float acc = 0.0f;
        for (int a = 0; a < 80; ++a)
            acc += cond_w[o * 80 + a] * y[a * 16 + f];
        condf[idx] = acc;
    }
}

// ---------------------------------------------------------------------------
// Conv + cond + gate:  U[256][T] = tanh(a)*sigmoid(g)
// z[r][t] = sum_k W[r][k] * X[k][t],  k=(c,tap), X[(c,0)][t]=h[c][t-d],
// X[(c,1)][t]=h[c][t].  Grid: (T/64, 8).  Each WG: 32 u-rows x 64 cols.
// ---------------------------------------------------------------------------
__global__ __launch_bounds__(256) void conv_gate_kernel(
    const float* __restrict__ h_in,
    float* __restrict__ U,
    const float* __restrict__ condf,   // [20480][16]
    const float* __restrict__ lw,      // [512][512] row-major (k = c*2+tap)
    const float* __restrict__ lb,      // [512]
    int d, int layer)
{
    __shared__ float Ws[32][64];   // [k][j] j<32: a-row rb*32+j ; j>=32: g-row
    __shared__ float Xs[32][64];   // [k][t']

    const int tid = threadIdx.x;
    const int t0  = blockIdx.x * 64;
    const int rb  = blockIdx.y;        // 0..7

    const int tc = tid & 15;           // col group (4 cols)
    const int tr = tid >> 4;           // row group (2 a-rows + 2 g-rows)

    float accA[2][4] = {{0.f}};
    float accG[2][4] = {{0.f}};

    // staging indices
    const int jw   = tid >> 2;           // 0..63
    const int kq   = (tid & 3) * 8;      // 0,8,16,24
    const int grow = (jw < 32) ? (rb * 32 + jw) : (256 + rb * 32 + (jw - 32));
    const float* wsrc = lw + (size_t)grow * 512;
    const int kk   = (tid >> 4) * 2;     // 0..30 step 2
    const int txs  = tid & 15;

    for (int kc = 0; kc < 512; kc += 32) {
        // ---- stage weights (transposed: Ws[k][row]) ----
        float4 w0 = *(const float4*)(wsrc + kc + kq);
        float4 w1 = *(const float4*)(wsrc + kc + kq + 4);
        Ws[kq + 0][jw] = w0.x; Ws[kq + 1][jw] = w0.y;
        Ws[kq + 2][jw] = w0.z; Ws[kq + 3][jw] = w0.w;
        Ws[kq + 4][jw] = w1.x; Ws[kq + 5][jw] = w1.y;
        Ws[kq + 6][jw] = w1.z; Ws[kq + 7][jw] = w1.w;
        // ---- stage X (shifted h rows) ----
        #pragma unroll
        for (int kx = 0; kx < 2; ++kx) {
            int kg  = kc + kk + kx;
            int c   = kg >> 1;
            int tap = kg & 1;
            int off = tap ? 0 : d;
            const float* hsrc = h_in + (size_t)c * T_LEN;
            #pragma unroll
            for (int j = 0; j < 4; ++j) {
                int tp   = txs + j * 16;
                int srct = t0 + tp - off;
                Xs[kk + kx][tp] = (srct >= 0) ? hsrc[srct] : 0.0f;
            }
        }
        __syncthreads();
        // ---- micro GEMM ----
        #pragma unroll
        for (int k = 0; k < 32; ++k) {
            const float2 wa = *(const float2*)&Ws[k][tr * 2];
            const float2 wg = *(const float2*)&Ws[k][32 + tr * 2];
            const float4 xv = *(const float4*)&Xs[k][tc * 4];
            const float xs[4] = {xv.x, xv.y, xv.z, xv.w};
            #pragma unroll
            for (int jc = 0; jc < 4; ++jc) {
                accA[0][jc] = fmaf(wa.x, xs[jc], accA[0][jc]);
                accA[1][jc] = fmaf(wa.y, xs[jc], accA[1][jc]);
                accG[0][jc] = fmaf(wg.x, xs[jc], accG[0][jc]);
                accG[1][jc] = fmaf(wg.y, xs[jc], accG[1][jc]);
            }
        }
        __syncthreads();
    }

    // ---- epilogue: cond + bias + gate, write U ----
    const int t = t0 + tc * 4;
    float fw[4]; int ci0[4], ci1[4];
    #pragma unroll
    for (int jc = 0; jc < 4; ++jc) {
        float pos = fmaxf((t + jc + 0.5f) * (1.0f / 256.0f) - 0.5f, 0.0f);
        int i0 = (int)pos;
        ci0[jc] = i0; ci1[jc] = min(i0 + 1, 15);
        fw[jc] = pos - (float)i0;
    }
    #pragma unroll
    for (int jr = 0; jr < 2; ++jr) {
        int ar = rb * 32 + tr * 2 + jr;
        const float* cfa = condf + (size_t)(layer * 512 + ar) * 16;
        const float* cfg = condf + (size_t)(layer * 512 + ar + 256) * 16;
        float ba = lb[ar], bg = lb[ar + 256];
        float u[4];
        #pragma unroll
        for (int jc = 0; jc < 4; ++jc) {
            float ca = cfa[ci0[jc]] * (1.f - fw[jc]) + cfa[ci1[jc]] * fw[jc];
            float cg = cfg[ci0[jc]] * (1.f - fw[jc]) + cfg[ci1[jc]] * fw[jc];
            float za = accA[jr][jc] + ba + ca;
            float zg = accG[jr][jc] + bg + cg;
            u[jc] = tanhf(za) * (1.0f / (1.0f + expf(-zg)));
        }
        *(float4*)(U + (size_t)ar * T_LEN + t) = make_float4(u[0], u[1], u[2], u[3]);
    }
}

// ---------------------------------------------------------------------------
// O = Wo @ U (+bo); rows<256 -> h_out = h_in + o; rows>=256 -> skip += o
// (last layer: 256 rows, all skip += o).  Grid: (T/64, 8 or 4).
// ---------------------------------------------------------------------------
__global__ __launch_bounds__(256) void layer_out_kernel(
    const float* __restrict__ U,
    const float* __restrict__ h_in,
    float* __restrict__ h_out,
    float* __restrict__ skip,
    const float* __restrict__ wow,   // [nrows][256]
    const float* __restrict__ wob,
    int is_last)
{
    __shared__ float Ws[32][64];
    __shared__ float Us[32][64];

    const int tid = threadIdx.x;
    const int t0  = blockIdx.x * 64;
    const int rb  = blockIdx.y;        // 64 rows each

    const int tc = tid & 15;
    const int tr = tid >> 4;

    float acc[4][4] = {{0.f}};

    const int jw = tid >> 2;
    const int kq = (tid & 3) * 8;
    const float* wsrc = wow + (size_t)(rb * 64 + jw) * 256;
    const int kk   = (tid >> 4) * 2;
    const int txs4 = (tid & 15) * 4;

    for (int kc = 0; kc < 256; kc += 32) {
        float4 w0 = *(const float4*)(wsrc + kc + kq);
        float4 w1 = *(const float4*)(wsrc + kc + kq + 4);
        Ws[kq + 0][jw] = w0.x; Ws[kq + 1][jw] = w0.y;
        Ws[kq + 2][jw] = w0.z; Ws[kq + 3][jw] = w0.w;
        Ws[kq + 4][jw] = w1.x; Ws[kq + 5][jw] = w1.y;
        Ws[kq + 6][jw] = w1.z; Ws[kq + 7][jw] = w1.w;
        #pragma unroll
        for (int kx = 0; kx < 2; ++kx)
            *(float4*)&Us[kk + kx][txs4] =
                *(const float4*)(U + (size_t)(kc + kk + kx) * T_LEN + t0 + txs4);
        __syncthreads();
        #pragma unroll
        for (int k = 0; k < 32; ++k) {
            const float4 w  = *(const float4*)&Ws[k][tr * 4];
            const float4 uv = *(const float4*)&Us[k][tc * 4];
            const float wr[4] = {w.x, w.y, w.z, w.w};
            const float us[4] = {uv.x, uv.y, uv.z, uv.w};
            #pragma unroll
            for (int jr = 0; jr < 4; ++jr)
                #pragma unroll
                for (int jc = 0; jc < 4; ++jc)
                    acc[jr][jc] = fmaf(wr[jr], us[jc], acc[jr][jc]);
        }
        __syncthreads();
    }

    const int t = t0 + tc * 4;
    #pragma unroll
    for (int jr = 0; jr < 4; ++jr) {
        int r = rb * 64 + tr * 4 + jr;
        float b = wob[r];
        float4 o = make_float4(acc[jr][0] + b, acc[jr][1] + b,
                               acc[jr][2] + b, acc[jr][3] + b);
        if (!is_last && r < 256) {
            float4 hv = *(const float4*)(h_in + (size_t)r * T_LEN + t);
            o.x += hv.x; o.y += hv.y; o.z += hv.z; o.w += hv.w;
            *(float4*)(h_out + (size_t)r * T_LEN + t) = o;
        } else {
            int sr = is_last ? r : (r - 256);
            float* sp = skip + (size_t)sr * T_LEN + t;
            float4 sv = *(const float4*)sp;
            sv.x += o.x; sv.y += o.y; sv.z += o.z; sv.w += o.w;
            *(float4*)sp = sv;
        }
    }
}

// ---------------------------------------------------------------------------
// Generic 256x256 GEMM for the head: Y = W @ f(X) + b, optional relu in/out
// ---------------------------------------------------------------------------
__global__ __launch_bounds__(256) void head_gemm_kernel(
    const float* __restrict__ X,
    float* __restrict__ Y,
    const float* __restrict__ Wm,    // [256][256]
    const float* __restrict__ bm,
    int relu_in, int relu_out)
{
    __shared__ float Ws[32][64];
    __shared__ float Us[32][64];

    const int tid = threadIdx.x;
    const int t0  = blockIdx.x * 64;
    const int rb  = blockIdx.y;        // 0..3, 64 rows each

    const int tc = tid & 15;
    const int tr = tid >> 4;

    float acc[4][4] = {{0.f}};

    const int jw = tid >> 2;
    const int kq = (tid & 3) * 8;
    const float* wsrc = Wm + (size_t)(rb * 64 + jw) * 256;
    const int kk   = (tid >> 4) * 2;
    const int txs4 = (tid & 15) * 4;

    for (int kc = 0; kc < 256; kc += 32) {
        float4 w0 = *(const float4*)(wsrc + kc + kq);
        float4 w1 = *(const float4*)(wsrc + kc + kq + 4);
        Ws[kq + 0][jw] = w0.x; Ws[kq + 1][jw] = w0.y;
        Ws[kq + 2][jw] = w0.z; Ws[kq + 3][jw] = w0.w;
        Ws[kq + 4][jw] = w1.x; Ws[kq + 5][jw] = w1.y;
        Ws[kq + 6][jw] = w1.z; Ws[kq + 7][jw] = w1.w;
        #pragma unroll
        for (int kx = 0; kx < 2; ++kx) {
            float4 xv = *(const float4*)(X + (size_t)(kc + kk + kx) * T_LEN + t0 + txs4);
            if (relu_in) {
                xv.x = fmaxf(xv.x, 0.f); xv.y = fmaxf(xv.y, 0.f);
                xv.z = fmaxf(xv.z, 0.f); xv.w = fmaxf(xv.w, 0.f);
            }
            *(float4*)&Us[kk + kx][txs4] = xv;
        }
        __syncthreads();
        #pragma unroll
        for (int k = 0; k < 32; ++k) {
            const float4 w  = *(const float4*)&Ws[k][tr * 4];
            const float4 uv = *(const float4*)&Us[k][tc * 4];
            const float wr[4] = {w.x, w.y, w.z, w.w};
            const float us[4] = {uv.x, uv.y, uv.z, uv.w};
            #pragma unroll
            for (int jr = 0; jr < 4; ++jr)
                #pragma unroll
                for (int jc = 0; jc < 4; ++jc)
                    acc[jr][jc] = fmaf(wr[jr], us[jc], acc[jr][jc]);
        }
        __syncthreads();
    }

    const int t = t0 + tc * 4;
    #pragma unroll
    for (int jr = 0; jr < 4; ++jr) {
        int r = rb * 64 + tr * 4 + jr;
        float b = bm[r];
        float4 o = make_float4(acc[jr][0] + b, acc[jr][1] + b,
                               acc[jr][2] + b, acc[jr][3] + b);
        if (relu_out) {
            o.x = fmaxf(o.x, 0.f); o.y = fmaxf(o.y, 0.f);
            o.z = fmaxf(o.z, 0.f); o.w = fmaxf(o.w, 0.f);
        }
        *(float4*)(Y + (size_t)r * T_LEN + t) = o;
    }
}

// ---------------------------------------------------------------------------
extern "C" void kernel_launch(void* const* d_in, const int* in_sizes, int n_in,
                              void* d_out, int out_size, void* d_ws, size_t ws_size,
                              hipStream_t stream)
{
    const int*   x       = (const int*)  d_in[0];
    const float* y       = (const float*)d_in[1];
    const float* emb_w   = (const float*)d_in[3];
    const float* cond_w  = (const float*)d_in[4];
    const float* layer_w = (const float*)d_in[5];
    const float* layer_b = (const float*)d_in[6];
    const float* wo_w    = (const float*)d_in[7];
    const float* wo_b    = (const float*)d_in[8];
    const float* lwo_w   = (const float*)d_in[9];
    const float* lwo_b   = (const float*)d_in[10];
    const float* e1w     = (const float*)d_in[11];
    const float* e1b     = (const float*)d_in[12];
    const float* e2w     = (const float*)d_in[13];
    const float* e2b     = (const float*)d_in[14];
    float* out = (float*)d_out;

    char* ws = (char*)d_ws;
    float* hA    = (float*)(ws);                          // 4 MB
    float* hB    = (float*)(ws + 4u  * 1024u * 1024u);    // 4 MB
    float* skip  = (float*)(ws + 8u  * 1024u * 1024u);    // 4 MB
    float* condf = (float*)(ws + 12u * 1024u * 1024u);    // 1.25 MB
    float* U     = (float*)(ws + 14u * 1024u * 1024u);    // 4 MB (reused as H1)

    embed_kernel<<<(256 * T_LEN + 255) / 256, 256, 0, stream>>>(x, emb_w, hA, skip);
    cond_kernel<<<(20480 * 16 + 255) / 256, 256, 0, stream>>>(cond_w, y, condf);

    static const int dil[10] = {1, 2, 4, 8, 16, 32, 64, 128, 256, 512};
    float* hin = hA;
    float* hout = hB;
    for (int i = 0; i < NLAYERS; ++i) {
        int d = dil[i % 10];
        int is_last = (i == NLAYERS - 1) ? 1 : 0;
        const float* wow = is_last ? lwo_w : (wo_w + (size_t)i * 512 * 256);
        const float* wob = is_last ? lwo_b : (wo_b + (size_t)i * 512);

        conv_gate_kernel<<<dim3(T_LEN / 64, 8), 256, 0, stream>>>(
            hin, U, condf,
            layer_w + (size_t)i * 512 * 512,
            layer_b + (size_t)i * 512,
            d, i);
        layer_out_kernel<<<dim3(T_LEN / 64, is_last ? 4 : 8), 256, 0, stream>>>(
            U, hin, hout, skip, wow, wob, is_last);

        float* tmp = hin; hin = hout; hout = tmp;
    }

    head_gemm_kernel<<<dim3(T_LEN / 64, 4), 256, 0, stream>>>(
        skip, U, e1w, e1b, 1, 1);
    head_gemm_kernel<<<dim3(T_LEN / 64, 4), 256, 0, stream>>>(
        U, out, e2w, e2b, 0, 0);
}

// Round 5
// 2255.983 us; speedup vs baseline: 6.3723x; 1.2394x over previous
//
#include <hip/hip_runtime.h>
#include <math.h>

#define T_LEN 4096

typedef __bf16 bf16x8 __attribute__((ext_vector_type(8)));
typedef float  f32x4  __attribute__((ext_vector_type(4)));

union U2 { __bf16 h[2]; unsigned int u; };
union U4 { __bf16 h[4]; uint2 u; };
union U8 { __bf16 h[8]; uint4 u; };

// ---------------------------------------------------------------------------
// embed: h[c][t]=tanh(emb_w[x[t]][c]) fp32 + hT[t][c] bf16 hi/lo + zero skip
// ---------------------------------------------------------------------------
__global__ __launch_bounds__(256) void embed_kernel(
    const int* __restrict__ x, const float* __restrict__ emb_w,
    float* __restrict__ h, __bf16* __restrict__ hT_hi, __bf16* __restrict__ hT_lo,
    float* __restrict__ skip)
{
    int idx = blockIdx.x * 256 + threadIdx.x;        // < 4096*128
    int c2 = (idx & 127) * 2;
    int t  = idx >> 7;
    float2 v = *(const float2*)&emb_w[(size_t)x[t] * 256 + c2];
    float e0 = tanhf(v.x), e1 = tanhf(v.y);
    h[(size_t)c2 * T_LEN + t]       = e0;
    h[(size_t)(c2 + 1) * T_LEN + t] = e1;
    U2 ph, pl;
    ph.h[0] = (__bf16)e0; ph.h[1] = (__bf16)e1;
    pl.h[0] = (__bf16)(e0 - (float)ph.h[0]);
    pl.h[1] = (__bf16)(e1 - (float)ph.h[1]);
    *(unsigned int*)(hT_hi + (size_t)t * 256 + c2) = ph.u;
    *(unsigned int*)(hT_lo + (size_t)t * 256 + c2) = pl.u;
    skip[idx * 2]     = 0.0f;
    skip[idx * 2 + 1] = 0.0f;
}

// ---------------------------------------------------------------------------
// condf[o][f] = sum_a cond_w[o][a] * y[a][f]   (o<20480, f<16, a<80)
// ---------------------------------------------------------------------------
__global__ __launch_bounds__(256) void cond_kernel(
    const float* __restrict__ cond_w, const float* __restrict__ y,
    float* __restrict__ condf)
{
    int idx = blockIdx.x * 256 + threadIdx.x;
    if (idx < 20480 * 16) {
        int o = idx >> 4, f = idx & 15;
        float acc = 0.0f;
        for (int a = 0; a < 80; ++a)
            acc += cond_w[o * 80 + a] * y[a * 16 + f];
        condf[idx] = acc;
    }
}

// ---------------------------------------------------------------------------
// skip -> ST[t][c] = relu(skip[c][t]) bf16 hi/lo  (head input)
// ---------------------------------------------------------------------------
__global__ __launch_bounds__(256) void skip_cvt_kernel(
    const float* __restrict__ skip,
    __bf16* __restrict__ ST_hi, __bf16* __restrict__ ST_lo)
{
    int idx = blockIdx.x * 256 + threadIdx.x;
    int c2 = (idx & 127) * 2;
    int t  = idx >> 7;
    float s0 = fmaxf(skip[(size_t)c2 * T_LEN + t], 0.0f);
    float s1 = fmaxf(skip[(size_t)(c2 + 1) * T_LEN + t], 0.0f);
    U2 ph, pl;
    ph.h[0] = (__bf16)s0; ph.h[1] = (__bf16)s1;
    pl.h[0] = (__bf16)(s0 - (float)ph.h[0]);
    pl.h[1] = (__bf16)(s1 - (float)ph.h[1]);
    *(unsigned int*)(ST_hi + (size_t)t * 256 + c2) = ph.u;
    *(unsigned int*)(ST_lo + (size_t)t * 256 + c2) = pl.u;
}

// ---------------------------------------------------------------------------
// Split-bf16 MFMA GEMM, WG tile 64(M) x 128(N), BK=32, 256 thr = 4 waves.
// MODE 0: conv+cond+gate  MODE 1: layer_out  MODE 2: last layer_out
// MODE 3: head1 (relu out, bf16)  MODE 4: head2 (fp32 out)
// ---------------------------------------------------------------------------
template<int MODE>
__global__ __launch_bounds__(256) void gemm_kernel(
    const float*  __restrict__ Wsrc,
    const __bf16* __restrict__ XT_hi, const __bf16* __restrict__ XT_lo,
    const float*  __restrict__ bias,
    const float*  __restrict__ condL,   // MODE0: condf + layer*512*16
    const float*  __restrict__ h_in,    // MODE1
    float*        __restrict__ h_out,   // MODE1
    __bf16*       __restrict__ OT_hi,   // MODE0:UT  MODE1:hT_next  MODE3:MT
    __bf16*       __restrict__ OT_lo,
    float*        __restrict__ skip,    // MODE1/2
    float*        __restrict__ outp,    // MODE4
    int d)
{
    constexpr int KTOT = (MODE == 0) ? 512 : 256;

    __shared__ __bf16 As_hi[64][40];
    __shared__ __bf16 As_lo[64][40];
    __shared__ __bf16 Bs_hi[128][40];
    __shared__ __bf16 Bs_lo[128][40];

    const int tid  = threadIdx.x;
    const int t0   = blockIdx.x * 128;
    const int by   = blockIdx.y;
    const int lane = tid & 63;
    const int wid  = tid >> 6;
    const int lg   = lane >> 4;
    const int lr   = lane & 15;

    // staging ids
    const int ra = tid & 63;           // A row
    const int jb = (tid >> 6) * 8;     // A k-offset (8 elems)
    const int tb = tid >> 1;           // B row (t')
    const int hf = tid & 1;            // B k-half (16 elems)

    int growA;
    if (MODE == 0) {
        int rp = by * 64 + ra;
        growA = (rp & 1) ? 256 + (rp >> 1) : (rp >> 1);
    } else {
        growA = by * 64 + ra;
    }

    f32x4 acc[4][2];
    #pragma unroll
    for (int mi = 0; mi < 4; ++mi)
        #pragma unroll
        for (int ni = 0; ni < 2; ++ni)
            acc[mi][ni] = (f32x4){0.f, 0.f, 0.f, 0.f};

    for (int kc = 0; kc < KTOT; kc += 32) {
        // ---- stage A (fp32 -> bf16 hi/lo) ----
        {
            float v[8];
            if (MODE == 0) {
                const int tap = (kc >= 256) ? 1 : 0;
                const float* src = Wsrc + (size_t)growA * 512 + 2 * ((kc & 255) + jb) + tap;
                #pragma unroll
                for (int j = 0; j < 8; ++j) v[j] = src[2 * j];
            } else {
                const float* src = Wsrc + (size_t)growA * KTOT + kc + jb;
                float4 a0 = *(const float4*)(src);
                float4 a1 = *(const float4*)(src + 4);
                v[0] = a0.x; v[1] = a0.y; v[2] = a0.z; v[3] = a0.w;
                v[4] = a1.x; v[5] = a1.y; v[6] = a1.z; v[7] = a1.w;
            }
            U8 ah, al;
            #pragma unroll
            for (int j = 0; j < 8; ++j) {
                __bf16 hi = (__bf16)v[j];
                ah.h[j] = hi;
                al.h[j] = (__bf16)(v[j] - (float)hi);
            }
            *(uint4*)&As_hi[ra][jb] = ah.u;
            *(uint4*)&As_lo[ra][jb] = al.u;
        }
        // ---- stage B: each thread stages a full 16-elem k-half (2x uint4
        //      per buffer; uint4 = 8 bf16 — staging only one was the r4 NaN bug)
        {
            int off  = (MODE == 0 && kc < 256) ? d : 0;
            int srow = t0 + tb - off;
            int cb   = ((MODE == 0) ? (kc & 255) : kc) + hf * 16;
            uint4 vh0, vh1, vl0, vl1;
            if (MODE == 0 && srow < 0) {
                vh0 = vh1 = vl0 = vl1 = make_uint4(0, 0, 0, 0);
            } else {
                const __bf16* bh = XT_hi + (size_t)srow * 256 + cb;
                const __bf16* bl = XT_lo + (size_t)srow * 256 + cb;
                vh0 = *(const uint4*)(bh);
                vh1 = *(const uint4*)(bh + 8);
                vl0 = *(const uint4*)(bl);
                vl1 = *(const uint4*)(bl + 8);
            }
            *(uint4*)&Bs_hi[tb][hf * 16]     = vh0;
            *(uint4*)&Bs_hi[tb][hf * 16 + 8] = vh1;
            *(uint4*)&Bs_lo[tb][hf * 16]     = vl0;
            *(uint4*)&Bs_lo[tb][hf * 16 + 8] = vl1;
        }
        __syncthreads();

        // ---- fragments + MFMA ----
        bf16x8 Ah[4], Al[4], Bh[2], Bl[2];
        #pragma unroll
        for (int mi = 0; mi < 4; ++mi) {
            Ah[mi] = *(const bf16x8*)&As_hi[mi * 16 + lr][8 * lg];
            Al[mi] = *(const bf16x8*)&As_lo[mi * 16 + lr][8 * lg];
        }
        #pragma unroll
        for (int ni = 0; ni < 2; ++ni) {
            Bh[ni] = *(const bf16x8*)&Bs_hi[wid * 32 + ni * 16 + lr][8 * lg];
            Bl[ni] = *(const bf16x8*)&Bs_lo[wid * 32 + ni * 16 + lr][8 * lg];
        }
        #pragma unroll
        for (int mi = 0; mi < 4; ++mi)
            #pragma unroll
            for (int ni = 0; ni < 2; ++ni) {
                acc[mi][ni] = __builtin_amdgcn_mfma_f32_16x16x32_bf16(Al[mi], Bh[ni], acc[mi][ni], 0, 0, 0);
                acc[mi][ni] = __builtin_amdgcn_mfma_f32_16x16x32_bf16(Ah[mi], Bl[ni], acc[mi][ni], 0, 0, 0);
                acc[mi][ni] = __builtin_amdgcn_mfma_f32_16x16x32_bf16(Ah[mi], Bh[ni], acc[mi][ni], 0, 0, 0);
            }
        __syncthreads();
    }

    // ---- epilogue ----
    #pragma unroll
    for (int ni = 0; ni < 2; ++ni) {
        const int t = t0 + wid * 32 + ni * 16 + lr;
        if (MODE == 0) {
            float pos = fmaxf((t + 0.5f) * 0.00390625f - 0.5f, 0.0f);
            int   i0  = (int)pos;
            int   i1  = min(i0 + 1, 15);
            float fw  = pos - (float)i0;
            #pragma unroll
            for (int mi = 0; mi < 4; ++mi) {
                int Rb = by * 64 + mi * 16 + 4 * lg;   // even
                float z[4];
                #pragma unroll
                for (int r = 0; r < 4; ++r) {
                    int R  = Rb + r;
                    int op = (R & 1) ? 256 + (R >> 1) : (R >> 1);
                    const float* cf = condL + op * 16;
                    float cv = cf[i0] * (1.0f - fw) + cf[i1] * fw;
                    z[r] = acc[mi][ni][r] + bias[op] + cv;
                }
                float u0 = tanhf(z[0]) * (1.0f / (1.0f + expf(-z[1])));
                float u1 = tanhf(z[2]) * (1.0f / (1.0f + expf(-z[3])));
                int cc = Rb >> 1;
                U2 ph, pl;
                ph.h[0] = (__bf16)u0; ph.h[1] = (__bf16)u1;
                pl.h[0] = (__bf16)(u0 - (float)ph.h[0]);
                pl.h[1] = (__bf16)(u1 - (float)ph.h[1]);
                *(unsigned int*)(OT_hi + (size_t)t * 256 + cc) = ph.u;
                *(unsigned int*)(OT_lo + (size_t)t * 256 + cc) = pl.u;
            }
        } else if (MODE == 1) {
            #pragma unroll
            for (int mi = 0; mi < 4; ++mi) {
                int Rb = by * 64 + mi * 16 + 4 * lg;
                if (by < 4) {
                    U4 ph, pl;
                    #pragma unroll
                    for (int r = 0; r < 4; ++r) {
                        int R = Rb + r;
                        float o  = acc[mi][ni][r] + bias[R];
                        float nv = h_in[(size_t)R * T_LEN + t] + o;
                        h_out[(size_t)R * T_LEN + t] = nv;
                        __bf16 hi = (__bf16)nv;
                        ph.h[r] = hi;
                        pl.h[r] = (__bf16)(nv - (float)hi);
                    }
                    *(uint2*)(OT_hi + (size_t)t * 256 + Rb) = ph.u;
                    *(uint2*)(OT_lo + (size_t)t * 256 + Rb) = pl.u;
                } else {
                    #pragma unroll
                    for (int r = 0; r < 4; ++r) {
                        int R = Rb + r;
                        float* sp = skip + (size_t)(R - 256) * T_LEN + t;
                        *sp += acc[mi][ni][r] + bias[R];
                    }
                }
            }
        } else if (MODE == 2) {
            #pragma unroll
            for (int mi = 0; mi < 4; ++mi) {
                int Rb = by * 64 + mi * 16 + 4 * lg;
                #pragma unroll
                for (int r = 0; r < 4; ++r) {
                    int R = Rb + r;
                    float* sp = skip + (size_t)R * T_LEN + t;
                    *sp += acc[mi][ni][r] + bias[R];
                }
            }
        } else if (MODE == 3) {
            #pragma unroll
            for (int mi = 0; mi < 4; ++mi) {
                int Rb = by * 64 + mi * 16 + 4 * lg;
                U4 ph, pl;
                #pragma unroll
                for (int r = 0; r < 4; ++r) {
                    int R = Rb + r;
                    float m = fmaxf(acc[mi][ni][r] + bias[R], 0.0f);
                    __bf16 hi = (__bf16)m;
                    ph.h[r] = hi;
                    pl.h[r] = (__bf16)(m - (float)hi);
                }
                *(uint2*)(OT_hi + (size_t)t * 256 + Rb) = ph.u;
                *(uint2*)(OT_lo + (size_t)t * 256 + Rb) = pl.u;
            }
        } else {  // MODE 4
            #pragma unroll
            for (int mi = 0; mi < 4; ++mi) {
                int Rb = by * 64 + mi * 16 + 4 * lg;
                #pragma unroll
                for (int r = 0; r < 4; ++r) {
                    int R = Rb + r;
                    outp[(size_t)R * T_LEN + t] = acc[mi][ni][r] + bias[R];
                }
            }
        }
    }
}

// ---------------------------------------------------------------------------
extern "C" void kernel_launch(void* const* d_in, const int* in_sizes, int n_in,
                              void* d_out, int out_size, void* d_ws, size_t ws_size,
                              hipStream_t stream)
{
    const int*   x       = (const int*)  d_in[0];
    const float* y       = (const float*)d_in[1];
    const float* emb_w   = (const float*)d_in[3];
    const float* cond_w  = (const float*)d_in[4];
    const float* layer_w = (const float*)d_in[5];
    const float* layer_b = (const float*)d_in[6];
    const float* wo_w    = (const float*)d_in[7];
    const float* wo_b    = (const float*)d_in[8];
    const float* lwo_w   = (const float*)d_in[9];
    const float* lwo_b   = (const float*)d_in[10];
    const float* e1w     = (const float*)d_in[11];
    const float* e1b     = (const float*)d_in[12];
    const float* e2w     = (const float*)d_in[13];
    const float* e2b     = (const float*)d_in[14];
    float* out = (float*)d_out;

    char* ws = (char*)d_ws;
    const size_t MB = 1024u * 1024u;
    float*  hA     = (float*)(ws);                 // 4 MB
    float*  hB     = (float*)(ws + 4 * MB);        // 4 MB
    float*  skip   = (float*)(ws + 8 * MB);        // 4 MB
    float*  condf  = (float*)(ws + 12 * MB);       // 1.31 MB
    __bf16* hTA_hi = (__bf16*)(ws + 14 * MB);      // 2 MB each
    __bf16* hTA_lo = (__bf16*)(ws + 16 * MB);
    __bf16* hTB_hi = (__bf16*)(ws + 18 * MB);
    __bf16* hTB_lo = (__bf16*)(ws + 20 * MB);
    __bf16* UT_hi  = (__bf16*)(ws + 22 * MB);
    __bf16* UT_lo  = (__bf16*)(ws + 24 * MB);

    embed_kernel<<<2048, 256, 0, stream>>>(x, emb_w, hA, hTA_hi, hTA_lo, skip);
    cond_kernel<<<(20480 * 16 + 255) / 256, 256, 0, stream>>>(cond_w, y, condf);

    static const int dil[10] = {1, 2, 4, 8, 16, 32, 64, 128, 256, 512};
    float*  hin  = hA;      float*  hout = hB;
    __bf16* hTi_hi = hTA_hi; __bf16* hTi_lo = hTA_lo;
    __bf16* hTo_hi = hTB_hi; __bf16* hTo_lo = hTB_lo;

    for (int i = 0; i < 40; ++i) {
        int d = dil[i % 10];
        const float* lw  = layer_w + (size_t)i * 512 * 512;
        const float* lb  = layer_b + (size_t)i * 512;
        const float* cL  = condf + (size_t)i * 512 * 16;

        gemm_kernel<0><<<dim3(32, 8), 256, 0, stream>>>(
            lw, hTi_hi, hTi_lo, lb, cL,
            nullptr, nullptr, UT_hi, UT_lo, nullptr, nullptr, d);

        if (i < 39) {
            gemm_kernel<1><<<dim3(32, 8), 256, 0, stream>>>(
                wo_w + (size_t)i * 512 * 256, UT_hi, UT_lo, wo_b + (size_t)i * 512,
                nullptr, hin, hout, hTo_hi, hTo_lo, skip, nullptr, 0);
            // swap buffers
            float* tf = hin; hin = hout; hout = tf;
            __bf16* t1 = hTi_hi; hTi_hi = hTo_hi; hTo_hi = t1;
            __bf16* t2 = hTi_lo; hTi_lo = hTo_lo; hTo_lo = t2;
        } else {
            gemm_kernel<2><<<dim3(32, 4), 256, 0, stream>>>(
                lwo_w, UT_hi, UT_lo, lwo_b,
                nullptr, nullptr, nullptr, nullptr, nullptr, skip, nullptr, 0);
        }
    }

    // head: ST = relu(skip) hi/lo (reuse UT buffers), MT reuse hTA
    skip_cvt_kernel<<<2048, 256, 0, stream>>>(skip, UT_hi, UT_lo);
    gemm_kernel<3><<<dim3(32, 4), 256, 0, stream>>>(
        e1w, UT_hi, UT_lo, e1b,
        nullptr, nullptr, nullptr, hTA_hi, hTA_lo, nullptr, nullptr, 0);
    gemm_kernel<4><<<dim3(32, 4), 256, 0, stream>>>(
        e2w, hTA_hi, hTA_lo, e2b,
        nullptr, nullptr, nullptr, nullptr, nullptr, nullptr, out, 0);
}

// Round 6
// 1813.824 us; speedup vs baseline: 7.9256x; 1.2438x over previous
//
#include <hip/hip_runtime.h>
#include <math.h>

#define T_LEN 4096

typedef __bf16 bf16x8 __attribute__((ext_vector_type(8)));
typedef float  f32x4  __attribute__((ext_vector_type(4)));

union U2 { __bf16 h[2]; unsigned int u; };
union U4 { __bf16 h[4]; uint2 u; };
union U8 { __bf16 h[8]; uint4 u; };

// async global->LDS, 16B per lane. LDS dest = wave-uniform base + lane*16.
// Global src is PER-LANE (each lane supplies its own full address).
__device__ __forceinline__ void gll16(const void* g, void* l) {
    __builtin_amdgcn_global_load_lds(
        (const __attribute__((address_space(1))) void*)g,
        (__attribute__((address_space(3))) void*)l, 16, 0, 0);
}

// ---------------------------------------------------------------------------
// embed: h[c][t]=tanh(emb_w[x[t]][c]) fp32 + hT[t][c] bf16 hi/lo + zero skip
// ---------------------------------------------------------------------------
__global__ __launch_bounds__(256) void embed_kernel(
    const int* __restrict__ x, const float* __restrict__ emb_w,
    float* __restrict__ h, __bf16* __restrict__ hT_hi, __bf16* __restrict__ hT_lo,
    float* __restrict__ skip)
{
    int idx = blockIdx.x * 256 + threadIdx.x;        // < 4096*128
    int c2 = (idx & 127) * 2;
    int t  = idx >> 7;
    float2 v = *(const float2*)&emb_w[(size_t)x[t] * 256 + c2];
    float e0 = tanhf(v.x), e1 = tanhf(v.y);
    h[(size_t)c2 * T_LEN + t]       = e0;
    h[(size_t)(c2 + 1) * T_LEN + t] = e1;
    U2 ph, pl;
    ph.h[0] = (__bf16)e0; ph.h[1] = (__bf16)e1;
    pl.h[0] = (__bf16)(e0 - (float)ph.h[0]);
    pl.h[1] = (__bf16)(e1 - (float)ph.h[1]);
    *(unsigned int*)(hT_hi + (size_t)t * 256 + c2) = ph.u;
    *(unsigned int*)(hT_lo + (size_t)t * 256 + c2) = pl.u;
    skip[idx * 2]     = 0.0f;
    skip[idx * 2 + 1] = 0.0f;
}

// ---------------------------------------------------------------------------
// condf[o][f] = sum_a cond_w[o][a] * y[a][f]
// ---------------------------------------------------------------------------
__global__ __launch_bounds__(256) void cond_kernel(
    const float* __restrict__ cond_w, const float* __restrict__ y,
    float* __restrict__ condf)
{
    int idx = blockIdx.x * 256 + threadIdx.x;
    if (idx < 20480 * 16) {
        int o = idx >> 4, f = idx & 15;
        float acc = 0.0f;
        for (int a = 0; a < 80; ++a)
            acc += cond_w[o * 80 + a] * y[a * 16 + f];
        condf[idx] = acc;
    }
}

// ---------------------------------------------------------------------------
// skip -> ST[t][c] = relu(skip[c][t]) bf16 hi/lo
// ---------------------------------------------------------------------------
__global__ __launch_bounds__(256) void skip_cvt_kernel(
    const float* __restrict__ skip,
    __bf16* __restrict__ ST_hi, __bf16* __restrict__ ST_lo)
{
    int idx = blockIdx.x * 256 + threadIdx.x;
    int c2 = (idx & 127) * 2;
    int t  = idx >> 7;
    float s0 = fmaxf(skip[(size_t)c2 * T_LEN + t], 0.0f);
    float s1 = fmaxf(skip[(size_t)(c2 + 1) * T_LEN + t], 0.0f);
    U2 ph, pl;
    ph.h[0] = (__bf16)s0; ph.h[1] = (__bf16)s1;
    pl.h[0] = (__bf16)(s0 - (float)ph.h[0]);
    pl.h[1] = (__bf16)(s1 - (float)ph.h[1]);
    *(unsigned int*)(ST_hi + (size_t)t * 256 + c2) = ph.u;
    *(unsigned int*)(ST_lo + (size_t)t * 256 + c2) = pl.u;
}

// ---------------------------------------------------------------------------
// Weight pre-conversion: fragment-linear bf16 hi/lo chunks.
// Chunk layout per (by,kc): [hl][mi][lane][8 bf16] = 4096 elems.
// conv: k = tap*256 + c, rows a/g-interleaved. 40*8*16*4*64 threads.
// ---------------------------------------------------------------------------
__global__ __launch_bounds__(256) void cvt_conv_kernel(
    const float* __restrict__ lw, __bf16* __restrict__ dst)
{
    int f = blockIdx.x * 256 + threadIdx.x;   // 1,310,720 total
    int lane = f & 63;
    int mi   = (f >> 6) & 3;
    int kc   = (f >> 8) & 15;
    int gb   = f >> 12;                        // L*8+by
    int lr = lane & 15, lg = lane >> 4;
    int by = gb & 7, L = gb >> 3;
    int row  = by * 64 + mi * 16 + lr;
    int grow = (row & 1) ? 256 + (row >> 1) : (row >> 1);
    int tap  = (kc >= 8) ? 1 : 0;
    int cb   = (kc & 7) * 32 + lg * 8;
    const float* src = lw + (size_t)L * 262144 + (size_t)grow * 512 + 2 * cb + tap;
    U8 hi, lo;
    #pragma unroll
    for (int j = 0; j < 8; ++j) {
        float v = src[2 * j];
        __bf16 h = (__bf16)v;
        hi.h[j] = h;
        lo.h[j] = (__bf16)(v - (float)h);
    }
    size_t base = (size_t)((gb * 16 + kc)) * 4096;
    *(uint4*)(dst + base + (size_t)mi * 512 + lane * 8)        = hi.u;
    *(uint4*)(dst + base + 2048 + (size_t)mi * 512 + lane * 8) = lo.u;
}

// generic [rows][256] fp32 matrix -> fragment-linear hi/lo. grid.y = mat idx.
__global__ __launch_bounds__(256) void cvt_mat_kernel(
    const float* __restrict__ src, __bf16* __restrict__ dst, int rows)
{
    int f = blockIdx.x * 256 + threadIdx.x;    // rows*32 threads
    if (f >= rows * 32) return;
    int lane = f & 63;
    int mi   = (f >> 6) & 3;
    int kc   = (f >> 8) & 7;
    int by   = f >> 11;
    int L    = blockIdx.y;
    int lr = lane & 15, lg = lane >> 4;
    int row = by * 64 + mi * 16 + lr;
    const float* s = src + (size_t)L * rows * 256 + (size_t)row * 256 + kc * 32 + lg * 8;
    float4 a0 = *(const float4*)(s);
    float4 a1 = *(const float4*)(s + 4);
    float v[8] = {a0.x, a0.y, a0.z, a0.w, a1.x, a1.y, a1.z, a1.w};
    U8 hi, lo;
    #pragma unroll
    for (int j = 0; j < 8; ++j) {
        __bf16 h = (__bf16)v[j];
        hi.h[j] = h;
        lo.h[j] = (__bf16)(v[j] - (float)h);
    }
    size_t base = (size_t)L * rows * 512 + (size_t)(by * 8 + kc) * 4096;
    *(uint4*)(dst + base + (size_t)mi * 512 + lane * 8)        = hi.u;
    *(uint4*)(dst + base + 2048 + (size_t)mi * 512 + lane * 8) = lo.u;
}

// ---------------------------------------------------------------------------
// Split-bf16 MFMA GEMM, tile 64(M)x128(N), BK=32, 4 waves, double-buffered
// global_load_lds staging from pre-converted fragment-linear weights.
// MODE 0: conv+cond+gate  MODE 1: layer_out  MODE 2: last layer_out
// MODE 3: head1 (relu, bf16 out)  MODE 4: head2 (fp32 out)
// ---------------------------------------------------------------------------
template<int MODE>
__global__ __launch_bounds__(256) void gemm_kernel(
    const __bf16* __restrict__ Wpre,
    const __bf16* __restrict__ XT_hi, const __bf16* __restrict__ XT_lo,
    const float*  __restrict__ bias,
    const float*  __restrict__ condL,
    const float*  __restrict__ h_in,
    float*        __restrict__ h_out,
    __bf16*       __restrict__ OT_hi,
    __bf16*       __restrict__ OT_lo,
    float*        __restrict__ skip,
    float*        __restrict__ outp,
    const __bf16* __restrict__ zbuf,
    int d)
{
    constexpr int NK = (MODE == 0) ? 16 : 8;

    __shared__ __bf16 Abuf[2][4096];   // [hl(2)][mi(4)][lane(64)][8]
    __shared__ __bf16 Bbuf[2][8192];   // [w(4)][hl(2)][ni(2)][lane(64)][8]

    const int tid  = threadIdx.x;
    const int t0   = blockIdx.x * 128;
    const int by   = blockIdx.y;
    const int lane = tid & 63;
    const int wid  = tid >> 6;
    const int lg   = lane >> 4;
    const int lr   = lane & 15;

    const __bf16* wbase = Wpre + (size_t)by * NK * 4096;

    f32x4 acc[4][2];
    #pragma unroll
    for (int mi = 0; mi < 4; ++mi)
        #pragma unroll
        for (int ni = 0; ni < 2; ++ni)
            acc[mi][ni] = (f32x4){0.f, 0.f, 0.f, 0.f};

    auto STAGE = [&](int buf, int kc) {
        // A: 2 chunks per wave (q = wid*2, wid*2+1), contiguous 1KB each
        const __bf16* ga = wbase + (size_t)kc * 4096 + (wid * 2) * 512 + lane * 8;
        gll16(ga,       &Abuf[buf][(wid * 2) * 512]);
        gll16(ga + 512, &Abuf[buf][(wid * 2 + 1) * 512]);
        // B: 4 chunks per wave (hl, ni); per-lane src (t-row = lr, k-ofs = lg)
        const int off  = (MODE == 0 && kc < 8) ? d : 0;
        const int colb = ((MODE == 0) ? (kc & 7) : kc) * 32 + lg * 8;
        #pragma unroll
        for (int ni = 0; ni < 2; ++ni) {
            int srow = t0 + wid * 32 + ni * 16 + lr - off;
            const __bf16* sh = (srow >= 0) ? XT_hi + (size_t)srow * 256 + colb : zbuf;
            const __bf16* sl = (srow >= 0) ? XT_lo + (size_t)srow * 256 + colb : zbuf;
            gll16(sh, &Bbuf[buf][(wid * 4 + ni) * 512]);
            gll16(sl, &Bbuf[buf][(wid * 4 + 2 + ni) * 512]);
        }
    };

    STAGE(0, 0);
    __syncthreads();

    for (int kc = 0; kc < NK; ++kc) {
        const int cur = kc & 1;
        if (kc + 1 < NK) STAGE(cur ^ 1, kc + 1);

        bf16x8 Ah[4], Al[4], Bh[2], Bl[2];
        #pragma unroll
        for (int mi = 0; mi < 4; ++mi) {
            Ah[mi] = *(const bf16x8*)&Abuf[cur][(mi)     * 512 + lane * 8];
            Al[mi] = *(const bf16x8*)&Abuf[cur][(4 + mi) * 512 + lane * 8];
        }
        #pragma unroll
        for (int ni = 0; ni < 2; ++ni) {
            Bh[ni] = *(const bf16x8*)&Bbuf[cur][(wid * 4 + ni)     * 512 + lane * 8];
            Bl[ni] = *(const bf16x8*)&Bbuf[cur][(wid * 4 + 2 + ni) * 512 + lane * 8];
        }
        #pragma unroll
        for (int mi = 0; mi < 4; ++mi)
            #pragma unroll
            for (int ni = 0; ni < 2; ++ni) {
                acc[mi][ni] = __builtin_amdgcn_mfma_f32_16x16x32_bf16(Al[mi], Bh[ni], acc[mi][ni], 0, 0, 0);
                acc[mi][ni] = __builtin_amdgcn_mfma_f32_16x16x32_bf16(Ah[mi], Bl[ni], acc[mi][ni], 0, 0, 0);
                acc[mi][ni] = __builtin_amdgcn_mfma_f32_16x16x32_bf16(Ah[mi], Bh[ni], acc[mi][ni], 0, 0, 0);
            }
        __syncthreads();
    }

    // ---- epilogue (C/D: col = lane&15 -> t, row = 4*lg + reg) ----
    #pragma unroll
    for (int ni = 0; ni < 2; ++ni) {
        const int t = t0 + wid * 32 + ni * 16 + lr;
        if (MODE == 0) {
            float pos = fmaxf((t + 0.5f) * 0.00390625f - 0.5f, 0.0f);
            int   i0  = (int)pos;
            int   i1  = min(i0 + 1, 15);
            float fw  = pos - (float)i0;
            #pragma unroll
            for (int mi = 0; mi < 4; ++mi) {
                int Rb = by * 64 + mi * 16 + 4 * lg;   // even
                float z[4];
                #pragma unroll
                for (int r = 0; r < 4; ++r) {
                    int R  = Rb + r;
                    int op = (R & 1) ? 256 + (R >> 1) : (R >> 1);
                    const float* cf = condL + op * 16;
                    float cv = cf[i0] * (1.0f - fw) + cf[i1] * fw;
                    z[r] = acc[mi][ni][r] + bias[op] + cv;
                }
                float u0 = tanhf(z[0]) * (1.0f / (1.0f + expf(-z[1])));
                float u1 = tanhf(z[2]) * (1.0f / (1.0f + expf(-z[3])));
                int cc = Rb >> 1;
                U2 ph, pl;
                ph.h[0] = (__bf16)u0; ph.h[1] = (__bf16)u1;
                pl.h[0] = (__bf16)(u0 - (float)ph.h[0]);
                pl.h[1] = (__bf16)(u1 - (float)ph.h[1]);
                *(unsigned int*)(OT_hi + (size_t)t * 256 + cc) = ph.u;
                *(unsigned int*)(OT_lo + (size_t)t * 256 + cc) = pl.u;
            }
        } else if (MODE == 1) {
            #pragma unroll
            for (int mi = 0; mi < 4; ++mi) {
                int Rb = by * 64 + mi * 16 + 4 * lg;
                if (by < 4) {
                    U4 ph, pl;
                    #pragma unroll
                    for (int r = 0; r < 4; ++r) {
                        int R = Rb + r;
                        float o  = acc[mi][ni][r] + bias[R];
                        float nv = h_in[(size_t)R * T_LEN + t] + o;
                        h_out[(size_t)R * T_LEN + t] = nv;
                        __bf16 hi = (__bf16)nv;
                        ph.h[r] = hi;
                        pl.h[r] = (__bf16)(nv - (float)hi);
                    }
                    *(uint2*)(OT_hi + (size_t)t * 256 + Rb) = ph.u;
                    *(uint2*)(OT_lo + (size_t)t * 256 + Rb) = pl.u;
                } else {
                    #pragma unroll
                    for (int r = 0; r < 4; ++r) {
                        int R = Rb + r;
                        float* sp = skip + (size_t)(R - 256) * T_LEN + t;
                        *sp += acc[mi][ni][r] + bias[R];
                    }
                }
            }
        } else if (MODE == 2) {
            #pragma unroll
            for (int mi = 0; mi < 4; ++mi) {
                int Rb = by * 64 + mi * 16 + 4 * lg;
                #pragma unroll
                for (int r = 0; r < 4; ++r) {
                    int R = Rb + r;
                    float* sp = skip + (size_t)R * T_LEN + t;
                    *sp += acc[mi][ni][r] + bias[R];
                }
            }
        } else if (MODE == 3) {
            #pragma unroll
            for (int mi = 0; mi < 4; ++mi) {
                int Rb = by * 64 + mi * 16 + 4 * lg;
                U4 ph, pl;
                #pragma unroll
                for (int r = 0; r < 4; ++r) {
                    int R = Rb + r;
                    float m = fmaxf(acc[mi][ni][r] + bias[R], 0.0f);
                    __bf16 hi = (__bf16)m;
                    ph.h[r] = hi;
                    pl.h[r] = (__bf16)(m - (float)hi);
                }
                *(uint2*)(OT_hi + (size_t)t * 256 + Rb) = ph.u;
                *(uint2*)(OT_lo + (size_t)t * 256 + Rb) = pl.u;
            }
        } else {  // MODE 4
            #pragma unroll
            for (int mi = 0; mi < 4; ++mi) {
                int Rb = by * 64 + mi * 16 + 4 * lg;
                #pragma unroll
                for (int r = 0; r < 4; ++r) {
                    int R = Rb + r;
                    outp[(size_t)R * T_LEN + t] = acc[mi][ni][r] + bias[R];
                }
            }
        }
    }
}

// ---------------------------------------------------------------------------
extern "C" void kernel_launch(void* const* d_in, const int* in_sizes, int n_in,
                              void* d_out, int out_size, void* d_ws, size_t ws_size,
                              hipStream_t stream)
{
    const int*   x       = (const int*)  d_in[0];
    const float* y       = (const float*)d_in[1];
    const float* emb_w   = (const float*)d_in[3];
    const float* cond_w  = (const float*)d_in[4];
    const float* layer_w = (const float*)d_in[5];
    const float* layer_b = (const float*)d_in[6];
    const float* wo_w    = (const float*)d_in[7];
    const float* wo_b    = (const float*)d_in[8];
    const float* lwo_w   = (const float*)d_in[9];
    const float* lwo_b   = (const float*)d_in[10];
    const float* e1w     = (const float*)d_in[11];
    const float* e1b     = (const float*)d_in[12];
    const float* e2w     = (const float*)d_in[13];
    const float* e2b     = (const float*)d_in[14];
    float* out = (float*)d_out;

    char* ws = (char*)d_ws;
    const size_t MB = 1024u * 1024u;
    float*  hA     = (float*)(ws);                 // 4 MB
    float*  hB     = (float*)(ws + 4 * MB);        // 4 MB
    float*  skip   = (float*)(ws + 8 * MB);        // 4 MB
    float*  condf  = (float*)(ws + 12 * MB);       // 1.31 MB
    __bf16* hTA_hi = (__bf16*)(ws + 14 * MB);      // 2 MB each
    __bf16* hTA_lo = (__bf16*)(ws + 16 * MB);
    __bf16* hTB_hi = (__bf16*)(ws + 18 * MB);
    __bf16* hTB_lo = (__bf16*)(ws + 20 * MB);
    __bf16* UT_hi  = (__bf16*)(ws + 22 * MB);
    __bf16* UT_lo  = (__bf16*)(ws + 24 * MB);
    __bf16* zbuf   = (__bf16*)(ws + 26 * MB);      // 4 KB, zeroed
    __bf16* convW  = (__bf16*)(ws + 28 * MB);      // 40 MB
    __bf16* woW    = (__bf16*)(ws + 68 * MB);      // 19.5 MB
    __bf16* lwoW   = (__bf16*)(ws + 88 * MB);      // 0.25 MB
    __bf16* e1W    = (__bf16*)(ws + 89 * MB);
    __bf16* e2W    = (__bf16*)(ws + 90 * MB);

    hipMemsetAsync(zbuf, 0, 4096, stream);

    cvt_conv_kernel<<<5120, 256, 0, stream>>>(layer_w, convW);
    cvt_mat_kernel<<<dim3(64, 39), 256, 0, stream>>>(wo_w, woW, 512);
    cvt_mat_kernel<<<dim3(32, 1), 256, 0, stream>>>(lwo_w, lwoW, 256);
    cvt_mat_kernel<<<dim3(32, 1), 256, 0, stream>>>(e1w, e1W, 256);
    cvt_mat_kernel<<<dim3(32, 1), 256, 0, stream>>>(e2w, e2W, 256);

    embed_kernel<<<2048, 256, 0, stream>>>(x, emb_w, hA, hTA_hi, hTA_lo, skip);
    cond_kernel<<<(20480 * 16 + 255) / 256, 256, 0, stream>>>(cond_w, y, condf);

    static const int dil[10] = {1, 2, 4, 8, 16, 32, 64, 128, 256, 512};
    float*  hin  = hA;      float*  hout = hB;
    __bf16* hTi_hi = hTA_hi; __bf16* hTi_lo = hTA_lo;
    __bf16* hTo_hi = hTB_hi; __bf16* hTo_lo = hTB_lo;

    for (int i = 0; i < 40; ++i) {
        int d = dil[i % 10];
        const float* lb = layer_b + (size_t)i * 512;
        const float* cL = condf + (size_t)i * 512 * 16;

        gemm_kernel<0><<<dim3(32, 8), 256, 0, stream>>>(
            convW + (size_t)i * 524288, hTi_hi, hTi_lo, lb, cL,
            nullptr, nullptr, UT_hi, UT_lo, nullptr, nullptr, zbuf, d);

        if (i < 39) {
            gemm_kernel<1><<<dim3(32, 8), 256, 0, stream>>>(
                woW + (size_t)i * 262144, UT_hi, UT_lo, wo_b + (size_t)i * 512,
                nullptr, hin, hout, hTo_hi, hTo_lo, skip, nullptr, zbuf, 0);
            float* tf = hin; hin = hout; hout = tf;
            __bf16* t1 = hTi_hi; hTi_hi = hTo_hi; hTo_hi = t1;
            __bf16* t2 = hTi_lo; hTi_lo = hTo_lo; hTo_lo = t2;
        } else {
            gemm_kernel<2><<<dim3(32, 4), 256, 0, stream>>>(
                lwoW, UT_hi, UT_lo, lwo_b,
                nullptr, nullptr, nullptr, nullptr, nullptr, skip, nullptr, zbuf, 0);
        }
    }

    skip_cvt_kernel<<<2048, 256, 0, stream>>>(skip, UT_hi, UT_lo);
    gemm_kernel<3><<<dim3(32, 4), 256, 0, stream>>>(
        e1W, UT_hi, UT_lo, e1b,
        nullptr, nullptr, nullptr, hTA_hi, hTA_lo, nullptr, nullptr, zbuf, 0);
    gemm_kernel<4><<<dim3(32, 4), 256, 0, stream>>>(
        e2W, hTA_hi, hTA_lo, e2b,
        nullptr, nullptr, nullptr, nullptr, nullptr, nullptr, out, zbuf, 0);
}

// Round 9
// 1191.502 us; speedup vs baseline: 12.0652x; 1.5223x over previous
//
#include <hip/hip_runtime.h>
#include <math.h>

#define T_LEN 4096

typedef __bf16 bf16x8 __attribute__((ext_vector_type(8)));
typedef float  f32x4  __attribute__((ext_vector_type(4)));

union U2 { __bf16 h[2]; unsigned int u; };
union U4 { __bf16 h[4]; uint2 u; };
union U8 { __bf16 h[8]; uint4 u; };

// async global->LDS, 16B/lane. LDS dest = wave-uniform base + lane*16.
__device__ __forceinline__ void gll16(const void* g, void* l) {
    __builtin_amdgcn_global_load_lds(
        (const __attribute__((address_space(1))) void*)g,
        (__attribute__((address_space(3))) void*)l, 16, 0, 0);
}

// fragment-linear activation layout ("BF"):
// elem (t,c) at (t>>4)*4096 + (c>>5)*512 + ((t&15) + 16*((c>>3)&3))*8 + (c&7)
__device__ __forceinline__ size_t bfidx(int t, int c) {
    return (size_t)(t >> 4) * 4096 + (size_t)((c >> 5) * 512)
         + (size_t)((((t & 15) + ((c >> 3) & 3) * 16)) * 8) + (c & 7);
}

// ---------------------------------------------------------------------------
// embed: h[c][t]=tanh(emb_w[x[t]][c]) fp32 + BF hi/lo + zero skip
// ---------------------------------------------------------------------------
__global__ __launch_bounds__(256) void embed_kernel(
    const int* __restrict__ x, const float* __restrict__ emb_w,
    float* __restrict__ h, __bf16* __restrict__ XF_hi, __bf16* __restrict__ XF_lo,
    float* __restrict__ skip)
{
    int idx = blockIdx.x * 256 + threadIdx.x;     // < 4096*128
    int t  = idx & 4095;
    int c2 = (idx >> 12) * 2;
    float2 v = *(const float2*)&emb_w[(size_t)x[t] * 256 + c2];
    float e0 = tanhf(v.x), e1 = tanhf(v.y);
    h[(size_t)c2 * T_LEN + t]       = e0;
    h[(size_t)(c2 + 1) * T_LEN + t] = e1;
    U2 ph, pl;
    ph.h[0] = (__bf16)e0; ph.h[1] = (__bf16)e1;
    pl.h[0] = (__bf16)(e0 - (float)ph.h[0]);
    pl.h[1] = (__bf16)(e1 - (float)ph.h[1]);
    size_t o = bfidx(t, c2);
    *(unsigned int*)(XF_hi + o) = ph.u;
    *(unsigned int*)(XF_lo + o) = pl.u;
    skip[idx * 2]     = 0.0f;
    skip[idx * 2 + 1] = 0.0f;
}

// ---------------------------------------------------------------------------
// condf[o][f] = sum_a cond_w[o][a] * y[a][f]
// ---------------------------------------------------------------------------
__global__ __launch_bounds__(256) void cond_kernel(
    const float* __restrict__ cond_w, const float* __restrict__ y,
    float* __restrict__ condf)
{
    int idx = blockIdx.x * 256 + threadIdx.x;
    if (idx < 20480 * 16) {
        int o = idx >> 4, f = idx & 15;
        float acc = 0.0f;
        for (int a = 0; a < 80; ++a)
            acc += cond_w[o * 80 + a] * y[a * 16 + f];
        condf[idx] = acc;
    }
}

// ---------------------------------------------------------------------------
// skip -> BF(relu(skip)) hi/lo
// ---------------------------------------------------------------------------
__global__ __launch_bounds__(256) void skip_cvt_kernel(
    const float* __restrict__ skip,
    __bf16* __restrict__ SF_hi, __bf16* __restrict__ SF_lo)
{
    int idx = blockIdx.x * 256 + threadIdx.x;
    int t  = idx & 4095;
    int c2 = (idx >> 12) * 2;
    float s0 = fmaxf(skip[(size_t)c2 * T_LEN + t], 0.0f);
    float s1 = fmaxf(skip[(size_t)(c2 + 1) * T_LEN + t], 0.0f);
    U2 ph, pl;
    ph.h[0] = (__bf16)s0; ph.h[1] = (__bf16)s1;
    pl.h[0] = (__bf16)(s0 - (float)ph.h[0]);
    pl.h[1] = (__bf16)(s1 - (float)ph.h[1]);
    size_t o = bfidx(t, c2);
    *(unsigned int*)(SF_hi + o) = ph.u;
    *(unsigned int*)(SF_lo + o) = pl.u;
}

// ---------------------------------------------------------------------------
// Weight pre-conversion -> fragment-linear bf16 hi/lo 4KB chunks per (by,kc)
// chunk = [hl(2)][mi(4)][lane(64)][8]
// ---------------------------------------------------------------------------
__global__ __launch_bounds__(256) void cvt_conv_kernel(
    const float* __restrict__ lw, __bf16* __restrict__ dst)
{
    int f = blockIdx.x * 256 + threadIdx.x;   // 1,310,720 total
    int lane = f & 63;
    int mi   = (f >> 6) & 3;
    int kc   = (f >> 8) & 15;
    int gb   = f >> 12;                        // L*8+by
    int lr = lane & 15, lg = lane >> 4;
    int by = gb & 7, L = gb >> 3;
    int row  = by * 64 + mi * 16 + lr;
    int grow = (row & 1) ? 256 + (row >> 1) : (row >> 1);
    int tap  = (kc >= 8) ? 1 : 0;
    int cb   = (kc & 7) * 32 + lg * 8;
    const float* src = lw + (size_t)L * 262144 + (size_t)grow * 512 + 2 * cb + tap;
    U8 hi, lo;
    #pragma unroll
    for (int j = 0; j < 8; ++j) {
        float v = src[2 * j];
        __bf16 h = (__bf16)v;
        hi.h[j] = h;
        lo.h[j] = (__bf16)(v - (float)h);
    }
    size_t base = (size_t)(gb * 16 + kc) * 4096;
    *(uint4*)(dst + base + (size_t)mi * 512 + lane * 8)        = hi.u;
    *(uint4*)(dst + base + 2048 + (size_t)mi * 512 + lane * 8) = lo.u;
}

__global__ __launch_bounds__(256) void cvt_mat_kernel(
    const float* __restrict__ src, __bf16* __restrict__ dst, int rows)
{
    int f = blockIdx.x * 256 + threadIdx.x;    // rows*32 threads
    if (f >= rows * 32) return;
    int lane = f & 63;
    int mi   = (f >> 6) & 3;
    int kc   = (f >> 8) & 7;
    int by   = f >> 11;
    int L    = blockIdx.y;
    int lr = lane & 15, lg = lane >> 4;
    int row = by * 64 + mi * 16 + lr;
    const float* s = src + (size_t)L * rows * 256 + (size_t)row * 256 + kc * 32 + lg * 8;
    float4 a0 = *(const float4*)(s);
    float4 a1 = *(const float4*)(s + 4);
    float v[8] = {a0.x, a0.y, a0.z, a0.w, a1.x, a1.y, a1.z, a1.w};
    U8 hi, lo;
    #pragma unroll
    for (int j = 0; j < 8; ++j) {
        __bf16 h = (__bf16)v[j];
        hi.h[j] = h;
        lo.h[j] = (__bf16)(v[j] - (float)h);
    }
    size_t base = (size_t)L * rows * 512 + (size_t)(by * 8 + kc) * 4096;
    *(uint4*)(dst + base + (size_t)mi * 512 + lane * 8)        = hi.u;
    *(uint4*)(dst + base + 2048 + (size_t)mi * 512 + lane * 8) = lo.u;
}

// ---------------------------------------------------------------------------
// Split-bf16 MFMA GEMM, tile 64(M)x64(N), 4 waves, grid (64, M/64) = 2 WG/CU.
// Double-buffered with COUNTED vmcnt (prefetch stays in flight across the
// barrier — no vmcnt(0) drain in the main loop).
// MODE 0: conv+cond+gate  MODE 1: layer_out  MODE 2: last layer_out
// MODE 3: head1 (relu)    MODE 4: head2 (fp32 out)
// ---------------------------------------------------------------------------
template<int MODE>
__global__ __launch_bounds__(256, 2) void gemm_kernel(
    const __bf16* __restrict__ Wpre,
    const __bf16* __restrict__ XF_hi, const __bf16* __restrict__ XF_lo,
    const float*  __restrict__ bias,
    const float*  __restrict__ condL,
    const float*  __restrict__ h_in,
    float*        __restrict__ h_out,
    __bf16*       __restrict__ OF_hi,
    __bf16*       __restrict__ OF_lo,
    float*        __restrict__ skip,
    float*        __restrict__ outp,
    const __bf16* __restrict__ zbuf,
    int d)
{
    constexpr int NK = (MODE == 0) ? 16 : 8;

    __shared__ __bf16 Ab[2][4096];   // 8 chunks: [hl*4+mi][512]
    __shared__ __bf16 Bb[2][8192];   // 16 chunks: [wid*4 + hl*2 + c2][512]

    const int tid  = threadIdx.x;
    const int t0   = blockIdx.x * 64;
    const int by   = blockIdx.y;
    const int lane = tid & 63;
    const int wid  = tid >> 6;
    const int lg   = lane >> 4;
    const int lr   = lane & 15;
    const int gw   = (t0 >> 4) + wid;        // this wave's t-group

    const __bf16* wbase = Wpre + (size_t)by * NK * 4096;
    const bool smalld = (MODE == 0) && (d < 16);

    f32x4 acc[4];
    #pragma unroll
    for (int mi = 0; mi < 4; ++mi) acc[mi] = (f32x4){0.f, 0.f, 0.f, 0.f};

    auto STAGE = [&](int buf, int kc) {
        // A: 2 contiguous 1KB chunks per wave
        const __bf16* ga = wbase + (size_t)kc * 4096 + (wid * 2) * 512 + lane * 8;
        gll16(ga,       &Ab[buf][(wid * 2) * 512]);
        gll16(ga + 512, &Ab[buf][(wid * 2 + 1) * 512]);
        // B
        const int kcb = (MODE == 0) ? (kc & 7) : kc;
        if (smalld && kc < 8) {
            // stage groups gw-1, gw (shift applied at fragment read)
            const __bf16* h1 = XF_hi + (size_t)gw * 4096 + kcb * 512 + lane * 8;
            const __bf16* l1 = XF_lo + (size_t)gw * 4096 + kcb * 512 + lane * 8;
            const __bf16* h0 = (gw >= 1) ? h1 - 4096 : zbuf + lane * 8;
            const __bf16* l0 = (gw >= 1) ? l1 - 4096 : zbuf + lane * 8;
            gll16(h0, &Bb[buf][(wid * 4 + 0) * 512]);
            gll16(h1, &Bb[buf][(wid * 4 + 1) * 512]);
            gll16(l0, &Bb[buf][(wid * 4 + 2) * 512]);
            gll16(l1, &Bb[buf][(wid * 4 + 3) * 512]);
        } else {
            const int off16 = (MODE == 0 && kc < 8) ? (d >> 4) : 0;
            const int gs = gw - off16;
            const __bf16* sh = (gs >= 0) ? XF_hi + (size_t)gs * 4096 + kcb * 512 + lane * 8
                                         : zbuf + lane * 8;
            const __bf16* sl = (gs >= 0) ? XF_lo + (size_t)gs * 4096 + kcb * 512 + lane * 8
                                         : zbuf + lane * 8;
            gll16(sh, &Bb[buf][(wid * 4 + 0) * 512]);
            gll16(sl, &Bb[buf][(wid * 4 + 2) * 512]);
        }
    };

    STAGE(0, 0);

    for (int kc = 0; kc < NK; ++kc) {
        const int cur = kc & 1;
        // Issue next-tile prefetch, then wait ONLY for the current tile's
        // loads (counted vmcnt): at most S(k+1)'s loads stay in flight
        // across the barrier.  vmcnt(4): >= all of S(k) complete in every
        // staging variant (L=4 or 6; over-waits at most 2 of S(k+1)).
        if (kc + 1 < NK) {
            STAGE(cur ^ 1, kc + 1);
            asm volatile("s_waitcnt vmcnt(4)" ::: "memory");
        } else {
            asm volatile("s_waitcnt vmcnt(0)" ::: "memory");
        }
        __builtin_amdgcn_sched_barrier(0);
        __builtin_amdgcn_s_barrier();

        bf16x8 Ah[4], Al[4], Bh, Bl;
        #pragma unroll
        for (int mi = 0; mi < 4; ++mi) {
            Ah[mi] = *(const bf16x8*)&Ab[cur][(mi)     * 512 + lane * 8];
            Al[mi] = *(const bf16x8*)&Ab[cur][(4 + mi) * 512 + lane * 8];
        }
        if (smalld && kc < 8) {
            int rr   = lr + 16 - d;                 // rotated row in 2-group window
            int q    = wid * 4 + (rr >> 4);
            int slot = (rr & 15) + 16 * lg;
            Bh = *(const bf16x8*)&Bb[cur][q * 512 + slot * 8];
            Bl = *(const bf16x8*)&Bb[cur][(q + 2) * 512 + slot * 8];
        } else {
            Bh = *(const bf16x8*)&Bb[cur][(wid * 4 + 0) * 512 + lane * 8];
            Bl = *(const bf16x8*)&Bb[cur][(wid * 4 + 2) * 512 + lane * 8];
        }
        #pragma unroll
        for (int mi = 0; mi < 4; ++mi) {
            acc[mi] = __builtin_amdgcn_mfma_f32_16x16x32_bf16(Al[mi], Bh, acc[mi], 0, 0, 0);
            acc[mi] = __builtin_amdgcn_mfma_f32_16x16x32_bf16(Ah[mi], Bl, acc[mi], 0, 0, 0);
            acc[mi] = __builtin_amdgcn_mfma_f32_16x16x32_bf16(Ah[mi], Bh, acc[mi], 0, 0, 0);
        }
        // All of this wave's ds_reads done -> safe for next iter to overwrite
        // buffer `cur` after the barrier.  (No vmcnt here: prefetch flies on.)
        asm volatile("s_waitcnt lgkmcnt(0)" ::: "memory");
        __builtin_amdgcn_sched_barrier(0);
        __builtin_amdgcn_s_barrier();
    }

    // ---- epilogue (C/D: col=lane&15 -> t, row=4*lg+reg) ----
    const int t = t0 + wid * 16 + lr;
    if (MODE == 0) {
        float pos = fmaxf((t + 0.5f) * 0.00390625f - 0.5f, 0.0f);
        int   i0  = (int)pos;
        int   i1  = min(i0 + 1, 15);
        float fw  = pos - (float)i0;
        #pragma unroll
        for (int mi = 0; mi < 4; ++mi) {
            int Rb = by * 64 + mi * 16 + 4 * lg;   // even
            float z[4];
            #pragma unroll
            for (int r = 0; r < 4; ++r) {
                int R  = Rb + r;
                int op = (R & 1) ? 256 + (R >> 1) : (R >> 1);
                const float* cf = condL + op * 16;
                float cv = cf[i0] * (1.0f - fw) + cf[i1] * fw;
                z[r] = acc[mi][r] + bias[op] + cv;
            }
            float u0 = tanhf(z[0]) * (1.0f / (1.0f + expf(-z[1])));
            float u1 = tanhf(z[2]) * (1.0f / (1.0f + expf(-z[3])));
            int cc = Rb >> 1;
            U2 ph, pl;
            ph.h[0] = (__bf16)u0; ph.h[1] = (__bf16)u1;
            pl.h[0] = (__bf16)(u0 - (float)ph.h[0]);
            pl.h[1] = (__bf16)(u1 - (float)ph.h[1]);
            size_t o = bfidx(t, cc);
            *(unsigned int*)(OF_hi + o) = ph.u;
            *(unsigned int*)(OF_lo + o) = pl.u;
        }
    } else if (MODE == 1) {
        #pragma unroll
        for (int mi = 0; mi < 4; ++mi) {
            int Rb = by * 64 + mi * 16 + 4 * lg;
            if (by < 4) {
                U4 ph, pl;
                #pragma unroll
                for (int r = 0; r < 4; ++r) {
                    int R = Rb + r;
                    float o  = acc[mi][r] + bias[R];
                    float nv = h_in[(size_t)R * T_LEN + t] + o;
                    h_out[(size_t)R * T_LEN + t] = nv;
                    __bf16 hi = (__bf16)nv;
                    ph.h[r] = hi;
                    pl.h[r] = (__bf16)(nv - (float)hi);
                }
                size_t o = bfidx(t, Rb);
                *(uint2*)(OF_hi + o) = ph.u;
                *(uint2*)(OF_lo + o) = pl.u;
            } else {
                #pragma unroll
                for (int r = 0; r < 4; ++r) {
                    int R = Rb + r;
                    float* sp = skip + (size_t)(R - 256) * T_LEN + t;
                    *sp += acc[mi][r] + bias[R];
                }
            }
        }
    } else if (MODE == 2) {
        #pragma unroll
        for (int mi = 0; mi < 4; ++mi) {
            int Rb = by * 64 + mi * 16 + 4 * lg;
            #pragma unroll
            for (int r = 0; r < 4; ++r) {
                int R = Rb + r;
                float* sp = skip + (size_t)R * T_LEN + t;
                *sp += acc[mi][r] + bias[R];
            }
        }
    } else if (MODE == 3) {
        #pragma unroll
        for (int mi = 0; mi < 4; ++mi) {
            int Rb = by * 64 + mi * 16 + 4 * lg;
            U4 ph, pl;
            #pragma unroll
            for (int r = 0; r < 4; ++r) {
                int R = Rb + r;
                float m = fmaxf(acc[mi][r] + bias[R], 0.0f);
                __bf16 hi = (__bf16)m;
                ph.h[r] = hi;
                pl.h[r] = (__bf16)(m - (float)hi);
            }
            size_t o = bfidx(t, Rb);
            *(uint2*)(OF_hi + o) = ph.u;
            *(uint2*)(OF_lo + o) = pl.u;
        }
    } else {  // MODE 4
        #pragma unroll
        for (int mi = 0; mi < 4; ++mi) {
            int Rb = by * 64 + mi * 16 + 4 * lg;
            #pragma unroll
            for (int r = 0; r < 4; ++r) {
                int R = Rb + r;
                outp[(size_t)R * T_LEN + t] = acc[mi][r] + bias[R];
            }
        }
    }
}

// ---------------------------------------------------------------------------
extern "C" void kernel_launch(void* const* d_in, const int* in_sizes, int n_in,
                              void* d_out, int out_size, void* d_ws, size_t ws_size,
                              hipStream_t stream)
{
    const int*   x       = (const int*)  d_in[0];
    const float* y       = (const float*)d_in[1];
    const float* emb_w   = (const float*)d_in[3];
    const float* cond_w  = (const float*)d_in[4];
    const float* layer_w = (const float*)d_in[5];
    const float* layer_b = (const float*)d_in[6];
    const float* wo_w    = (const float*)d_in[7];
    const float* wo_b    = (const float*)d_in[8];
    const float* lwo_w   = (const float*)d_in[9];
    const float* lwo_b   = (const float*)d_in[10];
    const float* e1w     = (const float*)d_in[11];
    const float* e1b     = (const float*)d_in[12];
    const float* e2w     = (const float*)d_in[13];
    const float* e2b     = (const float*)d_in[14];
    float* out = (float*)d_out;

    char* ws = (char*)d_ws;
    const size_t MB = 1024u * 1024u;
    float*  hA     = (float*)(ws);                 // 4 MB
    float*  hB     = (float*)(ws + 4 * MB);        // 4 MB
    float*  skip   = (float*)(ws + 8 * MB);        // 4 MB
    float*  condf  = (float*)(ws + 12 * MB);       // 1.31 MB
    __bf16* hFA_hi = (__bf16*)(ws + 14 * MB);      // 2 MB each
    __bf16* hFA_lo = (__bf16*)(ws + 16 * MB);
    __bf16* hFB_hi = (__bf16*)(ws + 18 * MB);
    __bf16* hFB_lo = (__bf16*)(ws + 20 * MB);
    __bf16* UF_hi  = (__bf16*)(ws + 22 * MB);
    __bf16* UF_lo  = (__bf16*)(ws + 24 * MB);
    __bf16* zbuf   = (__bf16*)(ws + 26 * MB);      // 4 KB, zeroed
    __bf16* convW  = (__bf16*)(ws + 28 * MB);      // 40 MB
    __bf16* woW    = (__bf16*)(ws + 68 * MB);      // 19.5 MB
    __bf16* lwoW   = (__bf16*)(ws + 88 * MB);      // 0.25 MB
    __bf16* e1W    = (__bf16*)(ws + 89 * MB);
    __bf16* e2W    = (__bf16*)(ws + 90 * MB);

    hipMemsetAsync(zbuf, 0, 4096, stream);

    cvt_conv_kernel<<<5120, 256, 0, stream>>>(layer_w, convW);
    cvt_mat_kernel<<<dim3(64, 39), 256, 0, stream>>>(wo_w, woW, 512);
    cvt_mat_kernel<<<dim3(32, 1), 256, 0, stream>>>(lwo_w, lwoW, 256);
    cvt_mat_kernel<<<dim3(32, 1), 256, 0, stream>>>(e1w, e1W, 256);
    cvt_mat_kernel<<<dim3(32, 1), 256, 0, stream>>>(e2w, e2W, 256);

    embed_kernel<<<2048, 256, 0, stream>>>(x, emb_w, hA, hFA_hi, hFA_lo, skip);
    cond_kernel<<<(20480 * 16 + 255) / 256, 256, 0, stream>>>(cond_w, y, condf);

    static const int dil[10] = {1, 2, 4, 8, 16, 32, 64, 128, 256, 512};
    float*  hin  = hA;      float*  hout = hB;
    __bf16* hFi_hi = hFA_hi; __bf16* hFi_lo = hFA_lo;
    __bf16* hFo_hi = hFB_hi; __bf16* hFo_lo = hFB_lo;

    for (int i = 0; i < 40; ++i) {
        int d = dil[i % 10];
        const float* lb = layer_b + (size_t)i * 512;
        const float* cL = condf + (size_t)i * 512 * 16;

        gemm_kernel<0><<<dim3(64, 8), 256, 0, stream>>>(
            convW + (size_t)i * 524288, hFi_hi, hFi_lo, lb, cL,
            nullptr, nullptr, UF_hi, UF_lo, nullptr, nullptr, zbuf, d);

        if (i < 39) {
            gemm_kernel<1><<<dim3(64, 8), 256, 0, stream>>>(
                woW + (size_t)i * 262144, UF_hi, UF_lo, wo_b + (size_t)i * 512,
                nullptr, hin, hout, hFo_hi, hFo_lo, skip, nullptr, zbuf, 0);
            float* tf = hin; hin = hout; hout = tf;
            __bf16* t1 = hFi_hi; hFi_hi = hFo_hi; hFo_hi = t1;
            __bf16* t2 = hFi_lo; hFi_lo = hFo_lo; hFo_lo = t2;
        } else {
            gemm_kernel<2><<<dim3(64, 4), 256, 0, stream>>>(
                lwoW, UF_hi, UF_lo, lwo_b,
                nullptr, nullptr, nullptr, nullptr, nullptr, skip, nullptr, zbuf, 0);
        }
    }

    skip_cvt_kernel<<<2048, 256, 0, stream>>>(skip, UF_hi, UF_lo);
    gemm_kernel<3><<<dim3(64, 4), 256, 0, stream>>>(
        e1W, UF_hi, UF_lo, e1b,
        nullptr, nullptr, nullptr, hFA_hi, hFA_lo, nullptr, nullptr, zbuf, 0);
    gemm_kernel<4><<<dim3(64, 4), 256, 0, stream>>>(
        e2W, hFA_hi, hFA_lo, e2b,
        nullptr, nullptr, nullptr, nullptr, nullptr, nullptr, out, zbuf, 0);
}

// Round 10
// 1081.853 us; speedup vs baseline: 13.2880x; 1.1014x over previous
//
#include <hip/hip_runtime.h>
#include <math.h>

#define T_LEN 4096

typedef __bf16 bf16x8 __attribute__((ext_vector_type(8)));
typedef float  f32x4  __attribute__((ext_vector_type(4)));

union U2 { __bf16 h[2]; unsigned int u; };
union U4 { __bf16 h[4]; uint2 u; };
union U8 { __bf16 h[8]; uint4 u; };

// async global->LDS, 16B/lane. LDS dest = wave-uniform base + lane*16.
__device__ __forceinline__ void gll16(const void* g, void* l) {
    __builtin_amdgcn_global_load_lds(
        (const __attribute__((address_space(1))) void*)g,
        (__attribute__((address_space(3))) void*)l, 16, 0, 0);
}

template<int N> __device__ __forceinline__ void vwait() {
    if constexpr (N == 0)      asm volatile("s_waitcnt vmcnt(0)" ::: "memory");
    else if constexpr (N == 4) asm volatile("s_waitcnt vmcnt(4)" ::: "memory");
    else if constexpr (N == 8) asm volatile("s_waitcnt vmcnt(8)" ::: "memory");
}

// fragment-linear activation layout ("BF"):
// elem (t,c) at (t>>4)*4096 + (c>>5)*512 + ((t&15) + 16*((c>>3)&3))*8 + (c&7)
__device__ __forceinline__ size_t bfidx(int t, int c) {
    return (size_t)(t >> 4) * 4096 + (size_t)((c >> 5) * 512)
         + (size_t)((((t & 15) + ((c >> 3) & 3) * 16)) * 8) + (c & 7);
}

// ---------------------------------------------------------------------------
// embed: BF(tanh(emb_w[x[t]])) hi/lo + zero skip   (no fp32 h shadow)
// ---------------------------------------------------------------------------
__global__ __launch_bounds__(256) void embed_kernel(
    const int* __restrict__ x, const float* __restrict__ emb_w,
    __bf16* __restrict__ XF_hi, __bf16* __restrict__ XF_lo,
    float* __restrict__ skip)
{
    int idx = blockIdx.x * 256 + threadIdx.x;     // < 4096*128
    int t  = idx & 4095;
    int c2 = (idx >> 12) * 2;
    float2 v = *(const float2*)&emb_w[(size_t)x[t] * 256 + c2];
    float e0 = tanhf(v.x), e1 = tanhf(v.y);
    U2 ph, pl;
    ph.h[0] = (__bf16)e0; ph.h[1] = (__bf16)e1;
    pl.h[0] = (__bf16)(e0 - (float)ph.h[0]);
    pl.h[1] = (__bf16)(e1 - (float)ph.h[1]);
    size_t o = bfidx(t, c2);
    *(unsigned int*)(XF_hi + o) = ph.u;
    *(unsigned int*)(XF_lo + o) = pl.u;
    skip[idx * 2]     = 0.0f;
    skip[idx * 2 + 1] = 0.0f;
}

// ---------------------------------------------------------------------------
// condf[o][f] = sum_a cond_w[o][a] * y[a][f]
// ---------------------------------------------------------------------------
__global__ __launch_bounds__(256) void cond_kernel(
    const float* __restrict__ cond_w, const float* __restrict__ y,
    float* __restrict__ condf)
{
    int idx = blockIdx.x * 256 + threadIdx.x;
    if (idx < 20480 * 16) {
        int o = idx >> 4, f = idx & 15;
        float acc = 0.0f;
        for (int a = 0; a < 80; ++a)
            acc += cond_w[o * 80 + a] * y[a * 16 + f];
        condf[idx] = acc;
    }
}

// ---------------------------------------------------------------------------
// Weight pre-conversion -> fragment-linear bf16 hi/lo 4KB chunks per (by,kc)
// chunk = [hl(2)][mi(4)][lane(64)][8]
// ---------------------------------------------------------------------------
__global__ __launch_bounds__(256) void cvt_conv_kernel(
    const float* __restrict__ lw, __bf16* __restrict__ dst)
{
    int f = blockIdx.x * 256 + threadIdx.x;   // 1,310,720 total
    int lane = f & 63;
    int mi   = (f >> 6) & 3;
    int kc   = (f >> 8) & 15;
    int gb   = f >> 12;                        // L*8+by
    int lr = lane & 15, lg = lane >> 4;
    int by = gb & 7, L = gb >> 3;
    int row  = by * 64 + mi * 16 + lr;
    int grow = (row & 1) ? 256 + (row >> 1) : (row >> 1);
    int tap  = (kc >= 8) ? 1 : 0;
    int cb   = (kc & 7) * 32 + lg * 8;
    const float* src = lw + (size_t)L * 262144 + (size_t)grow * 512 + 2 * cb + tap;
    U8 hi, lo;
    #pragma unroll
    for (int j = 0; j < 8; ++j) {
        float v = src[2 * j];
        __bf16 h = (__bf16)v;
        hi.h[j] = h;
        lo.h[j] = (__bf16)(v - (float)h);
    }
    size_t base = (size_t)(gb * 16 + kc) * 4096;
    *(uint4*)(dst + base + (size_t)mi * 512 + lane * 8)        = hi.u;
    *(uint4*)(dst + base + 2048 + (size_t)mi * 512 + lane * 8) = lo.u;
}

__global__ __launch_bounds__(256) void cvt_mat_kernel(
    const float* __restrict__ src, __bf16* __restrict__ dst, int rows)
{
    int f = blockIdx.x * 256 + threadIdx.x;    // rows*32 threads
    if (f >= rows * 32) return;
    int lane = f & 63;
    int mi   = (f >> 6) & 3;
    int kc   = (f >> 8) & 7;
    int by   = f >> 11;
    int L    = blockIdx.y;
    int lr = lane & 15, lg = lane >> 4;
    int row = by * 64 + mi * 16 + lr;
    const float* s = src + (size_t)L * rows * 256 + (size_t)row * 256 + kc * 32 + lg * 8;
    float4 a0 = *(const float4*)(s);
    float4 a1 = *(const float4*)(s + 4);
    float v[8] = {a0.x, a0.y, a0.z, a0.w, a1.x, a1.y, a1.z, a1.w};
    U8 hi, lo;
    #pragma unroll
    for (int j = 0; j < 8; ++j) {
        __bf16 h = (__bf16)v[j];
        hi.h[j] = h;
        lo.h[j] = (__bf16)(v[j] - (float)h);
    }
    size_t base = (size_t)L * rows * 512 + (size_t)(by * 8 + kc) * 4096;
    *(uint4*)(dst + base + (size_t)mi * 512 + lane * 8)        = hi.u;
    *(uint4*)(dst + base + 2048 + (size_t)mi * 512 + lane * 8) = lo.u;
}

// ---------------------------------------------------------------------------
// Split-bf16 MFMA GEMM, tile 64Mx64N, 4 waves.
// Triple-buffered, prefetch-2-ahead, counted vmcnt (8/4/0).
// SD=1 (conv d<16): B keeps 2 t-groups (16 chunks), LDS 72KB, 2 WG/CU.
// SD=0 (everything else): B packed to 8 chunks, LDS 48KB, 3 WG/CU.
// MODE 0: conv+cond+gate  MODE 1: layer_out (residual from HFI hi/lo)
// MODE 2: last layer_out + skip finalize + relu -> SF
// MODE 3: head1 (relu)    MODE 4: head2 (fp32 out)
// ---------------------------------------------------------------------------
template<int MODE, int SD>
__global__ __launch_bounds__(256, (MODE == 0 && SD) ? 2 : 3) void gemm_kernel(
    const __bf16* __restrict__ Wpre,
    const __bf16* __restrict__ XF_hi, const __bf16* __restrict__ XF_lo,
    const float*  __restrict__ bias,
    const float*  __restrict__ condL,
    const __bf16* __restrict__ HFI_hi,  // MODE1: prev-h hi
    const __bf16* __restrict__ HFI_lo,  // MODE1: prev-h lo
    __bf16*       __restrict__ OF_hi,
    __bf16*       __restrict__ OF_lo,
    float*        __restrict__ skip,
    float*        __restrict__ outp,
    const __bf16* __restrict__ zbuf,
    int d)
{
    constexpr int NK  = (MODE == 0) ? 16 : 8;
    constexpr int BCH = (MODE == 0 && SD) ? 8192 : 4096;

    __shared__ __bf16 Ab[3][4096];
    __shared__ __bf16 Bb[3][BCH];

    const int tid  = threadIdx.x;
    const int t0   = blockIdx.x * 64;
    const int by   = blockIdx.y;
    const int lane = tid & 63;
    const int wid  = tid >> 6;
    const int lg   = lane >> 4;
    const int lr   = lane & 15;
    const int gw   = (t0 >> 4) + wid;        // this wave's t-group

    const __bf16* wbase = Wpre + (size_t)by * NK * 4096;

    f32x4 acc[4];
    #pragma unroll
    for (int mi = 0; mi < 4; ++mi) acc[mi] = (f32x4){0.f, 0.f, 0.f, 0.f};

    auto STAGE = [&](int buf, int kc) {
        // A: 2 contiguous 1KB chunks per wave
        const __bf16* ga = wbase + (size_t)kc * 4096 + (wid * 2) * 512 + lane * 8;
        gll16(ga,       &Ab[buf][(wid * 2) * 512]);
        gll16(ga + 512, &Ab[buf][(wid * 2 + 1) * 512]);
        const int kcb = (MODE == 0) ? (kc & 7) : kc;
        if constexpr (MODE == 0 && SD) {
            if (kc < 8) {
                // stage t-groups gw-1, gw (shift applied at fragment read)
                const __bf16* h1 = XF_hi + (size_t)gw * 4096 + kcb * 512 + lane * 8;
                const __bf16* l1 = XF_lo + (size_t)gw * 4096 + kcb * 512 + lane * 8;
                const __bf16* h0 = (gw >= 1) ? h1 - 4096 : zbuf + lane * 8;
                const __bf16* l0 = (gw >= 1) ? l1 - 4096 : zbuf + lane * 8;
                gll16(h0, &Bb[buf][(wid * 4 + 0) * 512]);
                gll16(h1, &Bb[buf][(wid * 4 + 1) * 512]);
                gll16(l0, &Bb[buf][(wid * 4 + 2) * 512]);
                gll16(l1, &Bb[buf][(wid * 4 + 3) * 512]);
            } else {   // tap1, no shift
                const __bf16* sh = XF_hi + (size_t)gw * 4096 + kcb * 512 + lane * 8;
                const __bf16* sl = XF_lo + (size_t)gw * 4096 + kcb * 512 + lane * 8;
                gll16(sh, &Bb[buf][(wid * 4 + 0) * 512]);
                gll16(sl, &Bb[buf][(wid * 4 + 2) * 512]);
            }
        } else {
            const int off16 = (MODE == 0 && kc < 8) ? (d >> 4) : 0;
            const int gs = gw - off16;
            const __bf16* sh = (gs >= 0) ? XF_hi + (size_t)gs * 4096 + kcb * 512 + lane * 8
                                         : zbuf + lane * 8;
            const __bf16* sl = (gs >= 0) ? XF_lo + (size_t)gs * 4096 + kcb * 512 + lane * 8
                                         : zbuf + lane * 8;
            gll16(sh, &Bb[buf][(wid * 2) * 512]);
            gll16(sl, &Bb[buf][(wid * 2 + 1) * 512]);
        }
    };

    STAGE(0, 0);
    STAGE(1, 1);

    int cur = 0;
    for (int kc = 0; kc < NK; ++kc) {
        int pre = cur + 2; if (pre >= 3) pre -= 3;
        // vmcnt ledger: after issuing S(k+2), allowed-outstanding =
        // loads(S(k+1)) + loads(S(k+2)) >= 8 in every variant -> vwait<8>
        // never under-waits; tail uses 4 / 0.
        if (kc + 2 < NK)      { STAGE(pre, kc + 2); vwait<8>(); }
        else if (kc + 1 < NK) { vwait<4>(); }
        else                  { vwait<0>(); }
        __builtin_amdgcn_sched_barrier(0);
        __builtin_amdgcn_s_barrier();

        bf16x8 Ah[4], Al[4], Bh, Bl;
        #pragma unroll
        for (int mi = 0; mi < 4; ++mi) {
            Ah[mi] = *(const bf16x8*)&Ab[cur][(mi)     * 512 + lane * 8];
            Al[mi] = *(const bf16x8*)&Ab[cur][(4 + mi) * 512 + lane * 8];
        }
        if constexpr (MODE == 0 && SD) {
            if (kc < 8) {
                int rr   = lr + 16 - d;                 // rotated row in 2-group window
                int q    = wid * 4 + (rr >> 4);
                int slot = (rr & 15) + 16 * lg;
                Bh = *(const bf16x8*)&Bb[cur][q * 512 + slot * 8];
                Bl = *(const bf16x8*)&Bb[cur][(q + 2) * 512 + slot * 8];
            } else {
                Bh = *(const bf16x8*)&Bb[cur][(wid * 4 + 0) * 512 + lane * 8];
                Bl = *(const bf16x8*)&Bb[cur][(wid * 4 + 2) * 512 + lane * 8];
            }
        } else {
            Bh = *(const bf16x8*)&Bb[cur][(wid * 2) * 512 + lane * 8];
            Bl = *(const bf16x8*)&Bb[cur][(wid * 2 + 1) * 512 + lane * 8];
        }
        __builtin_amdgcn_s_setprio(1);
        #pragma unroll
        for (int mi = 0; mi < 4; ++mi) {
            acc[mi] = __builtin_amdgcn_mfma_f32_16x16x32_bf16(Al[mi], Bh, acc[mi], 0, 0, 0);
            acc[mi] = __builtin_amdgcn_mfma_f32_16x16x32_bf16(Ah[mi], Bl, acc[mi], 0, 0, 0);
            acc[mi] = __builtin_amdgcn_mfma_f32_16x16x32_bf16(Ah[mi], Bh, acc[mi], 0, 0, 0);
        }
        __builtin_amdgcn_s_setprio(0);
        // reads of buf `cur` retired before the barrier -> next STAGE may
        // overwrite it ((k+2)%3 == (k-1)%3).
        asm volatile("s_waitcnt lgkmcnt(0)" ::: "memory");
        __builtin_amdgcn_sched_barrier(0);
        __builtin_amdgcn_s_barrier();
        ++cur; if (cur == 3) cur = 0;
    }

    // ---- epilogue (C/D: col=lane&15 -> t, row=4*lg+reg) ----
    const int t = t0 + wid * 16 + lr;
    if (MODE == 0) {
        float pos = fmaxf((t + 0.5f) * 0.00390625f - 0.5f, 0.0f);
        int   i0  = (int)pos;
        int   i1  = min(i0 + 1, 15);
        float fw  = pos - (float)i0;
        #pragma unroll
        for (int mi = 0; mi < 4; ++mi) {
            int Rb = by * 64 + mi * 16 + 4 * lg;   // even
            float z[4];
            #pragma unroll
            for (int r = 0; r < 4; ++r) {
                int R  = Rb + r;
                int op = (R & 1) ? 256 + (R >> 1) : (R >> 1);
                const float* cf = condL + op * 16;
                float cv = cf[i0] * (1.0f - fw) + cf[i1] * fw;
                z[r] = acc[mi][r] + bias[op] + cv;
            }
            float u0 = tanhf(z[0]) * (1.0f / (1.0f + expf(-z[1])));
            float u1 = tanhf(z[2]) * (1.0f / (1.0f + expf(-z[3])));
            int cc = Rb >> 1;
            U2 ph, pl;
            ph.h[0] = (__bf16)u0; ph.h[1] = (__bf16)u1;
            pl.h[0] = (__bf16)(u0 - (float)ph.h[0]);
            pl.h[1] = (__bf16)(u1 - (float)ph.h[1]);
            size_t o = bfidx(t, cc);
            *(unsigned int*)(OF_hi + o) = ph.u;
            *(unsigned int*)(OF_lo + o) = pl.u;
        }
    } else if (MODE == 1) {
        #pragma unroll
        for (int mi = 0; mi < 4; ++mi) {
            int Rb = by * 64 + mi * 16 + 4 * lg;
            if (by < 4) {
                size_t o = bfidx(t, Rb);
                U4 hin, lin;
                hin.u = *(const uint2*)(HFI_hi + o);
                lin.u = *(const uint2*)(HFI_lo + o);
                U4 ph, pl;
                #pragma unroll
                for (int r = 0; r < 4; ++r) {
                    int R = Rb + r;
                    float hv = (float)hin.h[r] + (float)lin.h[r];
                    float nv = hv + acc[mi][r] + bias[R];
                    __bf16 hi = (__bf16)nv;
                    ph.h[r] = hi;
                    pl.h[r] = (__bf16)(nv - (float)hi);
                }
                *(uint2*)(OF_hi + o) = ph.u;
                *(uint2*)(OF_lo + o) = pl.u;
            } else {
                #pragma unroll
                for (int r = 0; r < 4; ++r) {
                    int R = Rb + r;
                    float* sp = skip + (size_t)(R - 256) * T_LEN + t;
                    *sp += acc[mi][r] + bias[R];
                }
            }
        }
    } else if (MODE == 2) {
        // final skip contribution + relu + split -> SF (OF)
        #pragma unroll
        for (int mi = 0; mi < 4; ++mi) {
            int Rb = by * 64 + mi * 16 + 4 * lg;
            U4 ph, pl;
            #pragma unroll
            for (int r = 0; r < 4; ++r) {
                int R = Rb + r;
                float sv = skip[(size_t)R * T_LEN + t] + acc[mi][r] + bias[R];
                float m  = fmaxf(sv, 0.0f);
                __bf16 hi = (__bf16)m;
                ph.h[r] = hi;
                pl.h[r] = (__bf16)(m - (float)hi);
            }
            size_t o = bfidx(t, Rb);
            *(uint2*)(OF_hi + o) = ph.u;
            *(uint2*)(OF_lo + o) = pl.u;
        }
    } else if (MODE == 3) {
        #pragma unroll
        for (int mi = 0; mi < 4; ++mi) {
            int Rb = by * 64 + mi * 16 + 4 * lg;
            U4 ph, pl;
            #pragma unroll
            for (int r = 0; r < 4; ++r) {
                int R = Rb + r;
                float m = fmaxf(acc[mi][r] + bias[R], 0.0f);
                __bf16 hi = (__bf16)m;
                ph.h[r] = hi;
                pl.h[r] = (__bf16)(m - (float)hi);
            }
            size_t o = bfidx(t, Rb);
            *(uint2*)(OF_hi + o) = ph.u;
            *(uint2*)(OF_lo + o) = pl.u;
        }
    } else {  // MODE 4
        #pragma unroll
        for (int mi = 0; mi < 4; ++mi) {
            int Rb = by * 64 + mi * 16 + 4 * lg;
            #pragma unroll
            for (int r = 0; r < 4; ++r) {
                int R = Rb + r;
                outp[(size_t)R * T_LEN + t] = acc[mi][r] + bias[R];
            }
        }
    }
}

// ---------------------------------------------------------------------------
extern "C" void kernel_launch(void* const* d_in, const int* in_sizes, int n_in,
                              void* d_out, int out_size, void* d_ws, size_t ws_size,
                              hipStream_t stream)
{
    const int*   x       = (const int*)  d_in[0];
    const float* y       = (const float*)d_in[1];
    const float* emb_w   = (const float*)d_in[3];
    const float* cond_w  = (const float*)d_in[4];
    const float* layer_w = (const float*)d_in[5];
    const float* layer_b = (const float*)d_in[6];
    const float* wo_w    = (const float*)d_in[7];
    const float* wo_b    = (const float*)d_in[8];
    const float* lwo_w   = (const float*)d_in[9];
    const float* lwo_b   = (const float*)d_in[10];
    const float* e1w     = (const float*)d_in[11];
    const float* e1b     = (const float*)d_in[12];
    const float* e2w     = (const float*)d_in[13];
    const float* e2b     = (const float*)d_in[14];
    float* out = (float*)d_out;

    char* ws = (char*)d_ws;
    const size_t MB = 1024u * 1024u;
    float*  skip   = (float*)(ws);                 // 4 MB
    float*  condf  = (float*)(ws + 4 * MB);        // 1.31 MB
    __bf16* hFA_hi = (__bf16*)(ws + 6 * MB);       // 2 MB each
    __bf16* hFA_lo = (__bf16*)(ws + 8 * MB);
    __bf16* hFB_hi = (__bf16*)(ws + 10 * MB);
    __bf16* hFB_lo = (__bf16*)(ws + 12 * MB);
    __bf16* UF_hi  = (__bf16*)(ws + 14 * MB);
    __bf16* UF_lo  = (__bf16*)(ws + 16 * MB);
    __bf16* zbuf   = (__bf16*)(ws + 18 * MB);      // 4 KB, zeroed
    __bf16* convW  = (__bf16*)(ws + 20 * MB);      // 40 MB
    __bf16* woW    = (__bf16*)(ws + 60 * MB);      // 19.5 MB
    __bf16* lwoW   = (__bf16*)(ws + 80 * MB);
    __bf16* e1W    = (__bf16*)(ws + 81 * MB);
    __bf16* e2W    = (__bf16*)(ws + 82 * MB);

    hipMemsetAsync(zbuf, 0, 4096, stream);

    cvt_conv_kernel<<<5120, 256, 0, stream>>>(layer_w, convW);
    cvt_mat_kernel<<<dim3(64, 39), 256, 0, stream>>>(wo_w, woW, 512);
    cvt_mat_kernel<<<dim3(32, 1), 256, 0, stream>>>(lwo_w, lwoW, 256);
    cvt_mat_kernel<<<dim3(32, 1), 256, 0, stream>>>(e1w, e1W, 256);
    cvt_mat_kernel<<<dim3(32, 1), 256, 0, stream>>>(e2w, e2W, 256);

    embed_kernel<<<2048, 256, 0, stream>>>(x, emb_w, hFA_hi, hFA_lo, skip);
    cond_kernel<<<(20480 * 16 + 255) / 256, 256, 0, stream>>>(cond_w, y, condf);

    static const int dil[10] = {1, 2, 4, 8, 16, 32, 64, 128, 256, 512};
    __bf16* hFi_hi = hFA_hi; __bf16* hFi_lo = hFA_lo;
    __bf16* hFo_hi = hFB_hi; __bf16* hFo_lo = hFB_lo;

    for (int i = 0; i < 40; ++i) {
        int d = dil[i % 10];
        const float* lb = layer_b + (size_t)i * 512;
        const float* cL = condf + (size_t)i * 512 * 16;
        const __bf16* cw = convW + (size_t)i * 524288;

        if (d < 16)
            gemm_kernel<0, 1><<<dim3(64, 8), 256, 0, stream>>>(
                cw, hFi_hi, hFi_lo, lb, cL, nullptr, nullptr,
                UF_hi, UF_lo, nullptr, nullptr, zbuf, d);
        else
            gemm_kernel<0, 0><<<dim3(64, 8), 256, 0, stream>>>(
                cw, hFi_hi, hFi_lo, lb, cL, nullptr, nullptr,
                UF_hi, UF_lo, nullptr, nullptr, zbuf, d);

        if (i < 39) {
            gemm_kernel<1, 0><<<dim3(64, 8), 256, 0, stream>>>(
                woW + (size_t)i * 262144, UF_hi, UF_lo, wo_b + (size_t)i * 512,
                nullptr, hFi_hi, hFi_lo, hFo_hi, hFo_lo, skip, nullptr, zbuf, 0);
            __bf16* t1 = hFi_hi; hFi_hi = hFo_hi; hFo_hi = t1;
            __bf16* t2 = hFi_lo; hFi_lo = hFo_lo; hFo_lo = t2;
        } else {
            // writes SF (relu'd skip, hi/lo) into the dead hFo pair
            gemm_kernel<2, 0><<<dim3(64, 4), 256, 0, stream>>>(
                lwoW, UF_hi, UF_lo, lwo_b,
                nullptr, nullptr, nullptr, hFo_hi, hFo_lo, skip, nullptr, zbuf, 0);
        }
    }

    // head: MT -> UF (dead after gemm<2>), out fp32
    gemm_kernel<3, 0><<<dim3(64, 4), 256, 0, stream>>>(
        e1W, hFo_hi, hFo_lo, e1b,
        nullptr, nullptr, nullptr, UF_hi, UF_lo, nullptr, nullptr, zbuf, 0);
    gemm_kernel<4, 0><<<dim3(64, 4), 256, 0, stream>>>(
        e2W, UF_hi, UF_lo, e2b,
        nullptr, nullptr, nullptr, nullptr, nullptr, nullptr, out, zbuf, 0);
}